// Round 1
// baseline (845.127 us; speedup 1.0000x reference)
//
#include <hip/hip_runtime.h>

#define N_NODES 50000
#define N_EDGES 800000
#define F 128
#define ALPHA 0.5f
#define BN_EPS 1e-5f

// ---------------- CSR build ----------------

__global__ void deg_kernel(const int* __restrict__ row, int* __restrict__ deg) {
    int e = blockIdx.x * blockDim.x + threadIdx.x;
    if (e < N_EDGES) atomicAdd(&deg[row[e]], 1);
}

__global__ void dinv_kernel(const int* __restrict__ deg, float* __restrict__ dinv) {
    int i = blockIdx.x * blockDim.x + threadIdx.x;
    if (i < N_NODES) {
        int d = deg[i];
        dinv[i] = d > 0 ? rsqrtf((float)d) : 0.f;
    }
}

// single-block inclusive scan -> exclusive rowptr
__global__ void scan_kernel(const int* __restrict__ deg, int* __restrict__ rowptr) {
    __shared__ int s[1024];
    int carry = 0;
    if (threadIdx.x == 0) rowptr[0] = 0;
    for (int base = 0; base < N_NODES; base += 1024) {
        int i = base + threadIdx.x;
        int v = (i < N_NODES) ? deg[i] : 0;
        s[threadIdx.x] = v;
        __syncthreads();
        for (int off = 1; off < 1024; off <<= 1) {
            int t = (threadIdx.x >= off) ? s[threadIdx.x - off] : 0;
            __syncthreads();
            s[threadIdx.x] += t;
            __syncthreads();
        }
        if (i < N_NODES) rowptr[i + 1] = s[threadIdx.x] + carry;
        carry += s[1023];          // uniform read of chunk total
        __syncthreads();           // protect s[] before next chunk's store
    }
}

__global__ void fill_kernel(const int* __restrict__ row, const int* __restrict__ col,
                            const int* __restrict__ rowptr, int* __restrict__ cursor,
                            const float* __restrict__ dinv,
                            int* __restrict__ colidx, float* __restrict__ wt) {
    int e = blockIdx.x * blockDim.x + threadIdx.x;
    if (e < N_EDGES) {
        int r = row[e], c = col[e];
        int pos = rowptr[r] + atomicAdd(&cursor[r], 1);
        colidx[pos] = c;
        wt[pos] = dinv[c];
    }
}

// ---------------- weight transpose (Wt[k][j] = W[j][k]) ----------------

__global__ void transpose_w(const float* __restrict__ W, float* __restrict__ Wt) {
    int idx = blockIdx.x * blockDim.x + threadIdx.x;
    if (idx < F * F) {
        int k = idx / F, j = idx % F;
        Wt[k * F + j] = W[j * F + k];
    }
}

// ---------------- fused high-pass (+ optional BN/ReLU on input) ----------------
// out[i][j] = f(h[i][j]) - ALPHA * dinv[i] * sum_e wt[e] * f(h[colidx[e]][j])
// f(x) = USEBN ? relu(x*scale[j]+shift[j]) : x
template <int USEBN>
__global__ __launch_bounds__(256) void hp_kernel(
        const float* __restrict__ h,
        const float* __restrict__ scale, const float* __restrict__ shift,
        const float* __restrict__ dinv, const int* __restrict__ rowptr,
        const int* __restrict__ colidx, const float* __restrict__ wt,
        float* __restrict__ out) {
    int j = threadIdx.x & 127;
    int i = blockIdx.x * 2 + (threadIdx.x >> 7);
    float sc = 1.f, sh = 0.f;
    if (USEBN) { sc = scale[j]; sh = shift[j]; }
    int e0 = rowptr[i], e1 = rowptr[i + 1];
    float acc = 0.f;
    for (int e = e0; e < e1; ++e) {
        int c = colidx[e];
        float w = wt[e];
        float x = h[(size_t)c * F + j];
        if (USEBN) x = fmaxf(x * sc + sh, 0.f);
        acc += w * x;
    }
    float x = h[(size_t)i * F + j];
    if (USEBN) x = fmaxf(x * sc + sh, 0.f);
    out[(size_t)i * F + j] = x - ALPHA * dinv[i] * acc;
}

// ---------------- f32 GEMM: out[M x 128] = A[M x 128] @ Wt(K-major) + bias ----------------
__global__ __launch_bounds__(256) void gemm_kernel(
        const float* __restrict__ A, const float* __restrict__ Wt,
        const float* __restrict__ bias, float* __restrict__ out, int M) {
    __shared__ float sA[64][128];
    int tid = threadIdx.x;
    int row0 = blockIdx.x * 64;
    {
        const float4* Ag = (const float4*)A;
        float4* s4 = (float4*)&sA[0][0];
        for (int t = tid; t < 64 * 32; t += 256) {
            int r = row0 + (t >> 5);
            s4[t] = (r < M) ? Ag[(size_t)r * 32 + (t & 31)]
                            : make_float4(0.f, 0.f, 0.f, 0.f);
        }
    }
    __syncthreads();
    int tx = tid & 31, ty = tid >> 5;  // ty 0..7 -> 8 rows each, tx -> 4 contiguous cols
    float acc[8][4] = {};
    #pragma unroll 4
    for (int k = 0; k < 128; ++k) {
        float4 w = ((const float4*)(Wt + (size_t)k * F))[tx];
        #pragma unroll
        for (int r = 0; r < 8; ++r) {
            float a = sA[ty * 8 + r][k];
            acc[r][0] += a * w.x;
            acc[r][1] += a * w.y;
            acc[r][2] += a * w.z;
            acc[r][3] += a * w.w;
        }
    }
    float4 b = ((const float4*)bias)[tx];
    #pragma unroll
    for (int r = 0; r < 8; ++r) {
        int rr = row0 + ty * 8 + r;
        if (rr < M) {
            float4 o = make_float4(acc[r][0] + b.x, acc[r][1] + b.y,
                                   acc[r][2] + b.z, acc[r][3] + b.w);
            ((float4*)out)[(size_t)rr * 32 + tx] = o;
        }
    }
}

// ---------------- BN stats (deterministic two-stage) ----------------
__global__ void stats_kernel(const float* __restrict__ h, float* __restrict__ partial) {
    int j = threadIdx.x;  // 128
    float s = 0.f, sq = 0.f;
    for (int i = blockIdx.x; i < N_NODES; i += gridDim.x) {
        float v = h[(size_t)i * F + j];
        s += v;
        sq += v * v;
    }
    partial[(size_t)blockIdx.x * 256 + j] = s;
    partial[(size_t)blockIdx.x * 256 + 128 + j] = sq;
}

__global__ void finalize_kernel(const float* __restrict__ partial,
                                const float* __restrict__ g, const float* __restrict__ bt,
                                float* __restrict__ scale, float* __restrict__ shift) {
    int j = threadIdx.x;  // 128
    float s = 0.f, sq = 0.f;
    for (int b = 0; b < 256; ++b) {
        s += partial[b * 256 + j];
        sq += partial[b * 256 + 128 + j];
    }
    float m = s / (float)N_NODES;
    float v = sq / (float)N_NODES - m * m;
    float sc = g[j] * rsqrtf(v + BN_EPS);
    scale[j] = sc;
    shift[j] = bt[j] - m * sc;
}

// ---------------- launch ----------------

extern "C" void kernel_launch(void* const* d_in, const int* in_sizes, int n_in,
                              void* d_out, int out_size, void* d_ws, size_t ws_size,
                              hipStream_t stream) {
    const float* x   = (const float*)d_in[0];
    const int*   ei  = (const int*)d_in[1];
    const float* W1  = (const float*)d_in[2];
    const float* b1  = (const float*)d_in[3];
    const float* W2  = (const float*)d_in[4];
    const float* b2  = (const float*)d_in[5];
    const float* W3  = (const float*)d_in[6];
    const float* b3  = (const float*)d_in[7];
    const float* g1  = (const float*)d_in[8];
    const float* bt1 = (const float*)d_in[9];
    const float* g2  = (const float*)d_in[10];
    const float* bt2 = (const float*)d_in[11];
    float* out = (float*)d_out;

    const int* row = ei;
    const int* col = ei + N_EDGES;

    char* ws = (char*)d_ws;
    size_t off = 0;
    auto alloc = [&](size_t bytes) -> void* {
        void* p = ws + off;
        off += (bytes + 255) & ~(size_t)255;
        return p;
    };
    int*   deg     = (int*)alloc(N_NODES * 4);
    int*   cursor  = (int*)alloc(N_NODES * 4);
    size_t zero_bytes = off;  // only deg+cursor need zeroing
    int*   rowptr  = (int*)alloc((N_NODES + 1) * 4);
    float* dinv    = (float*)alloc(N_NODES * 4);
    int*   colidx  = (int*)alloc((size_t)N_EDGES * 4);
    float* wt      = (float*)alloc((size_t)N_EDGES * 4);
    float* Wt1     = (float*)alloc(F * F * 4);
    float* Wt2     = (float*)alloc(F * F * 4);
    float* Wt3     = (float*)alloc(F * F * 4);
    float* partial = (float*)alloc(256 * 256 * 4);
    float* scale1  = (float*)alloc(F * 4);
    float* shift1  = (float*)alloc(F * 4);
    float* scale2  = (float*)alloc(F * 4);
    float* shift2  = (float*)alloc(F * 4);
    float* hp      = (float*)alloc((size_t)N_NODES * F * 4);
    (void)ws_size; (void)n_in; (void)in_sizes; (void)out_size;

    hipMemsetAsync(d_ws, 0, zero_bytes, stream);

    transpose_w<<<(F * F + 255) / 256, 256, 0, stream>>>(W1, Wt1);
    transpose_w<<<(F * F + 255) / 256, 256, 0, stream>>>(W2, Wt2);
    transpose_w<<<(F * F + 255) / 256, 256, 0, stream>>>(W3, Wt3);

    deg_kernel<<<(N_EDGES + 255) / 256, 256, 0, stream>>>(row, deg);
    dinv_kernel<<<(N_NODES + 255) / 256, 256, 0, stream>>>(deg, dinv);
    scan_kernel<<<1, 1024, 0, stream>>>(deg, rowptr);
    fill_kernel<<<(N_EDGES + 255) / 256, 256, 0, stream>>>(row, col, rowptr, cursor,
                                                           dinv, colidx, wt);

    const int hp_grid = N_NODES / 2;           // 2 rows per 256-thread block
    const int gemm_grid = (N_NODES + 63) / 64; // 782

    // layer 0
    hp_kernel<0><<<hp_grid, 256, 0, stream>>>(x, nullptr, nullptr, dinv, rowptr,
                                              colidx, wt, hp);
    gemm_kernel<<<gemm_grid, 256, 0, stream>>>(hp, Wt1, b1, out, N_NODES);
    stats_kernel<<<256, 128, 0, stream>>>(out, partial);
    finalize_kernel<<<1, 128, 0, stream>>>(partial, g1, bt1, scale1, shift1);

    // layer 1
    hp_kernel<1><<<hp_grid, 256, 0, stream>>>(out, scale1, shift1, dinv, rowptr,
                                              colidx, wt, hp);
    gemm_kernel<<<gemm_grid, 256, 0, stream>>>(hp, Wt2, b2, out, N_NODES);
    stats_kernel<<<256, 128, 0, stream>>>(out, partial);
    finalize_kernel<<<1, 128, 0, stream>>>(partial, g2, bt2, scale2, shift2);

    // layer 2 (output)
    hp_kernel<1><<<hp_grid, 256, 0, stream>>>(out, scale2, shift2, dinv, rowptr,
                                              colidx, wt, hp);
    gemm_kernel<<<gemm_grid, 256, 0, stream>>>(hp, Wt3, b3, out, N_NODES);
}

// Round 2
// 604.849 us; speedup vs baseline: 1.3973x; 1.3973x over previous
//
#include <hip/hip_runtime.h>

#define N_NODES 50000
#define N_EDGES 800000
#define F 128
#define ALPHA 0.5f
#define BN_EPS 1e-5f
#define NB_SCAN ((N_NODES + 255) / 256)   // 196
#define GEMM_NBLK ((N_NODES + 63) / 64)   // 782

// ---------------- CSR build ----------------

__global__ void deg_kernel(const int* __restrict__ row, int* __restrict__ deg) {
    int e = blockIdx.x * blockDim.x + threadIdx.x;
    if (e < N_EDGES) atomicAdd(&deg[row[e]], 1);
}

__global__ void dinv_kernel(const int* __restrict__ deg, float* __restrict__ dinv) {
    int i = blockIdx.x * blockDim.x + threadIdx.x;
    if (i < N_NODES) {
        int d = deg[i];
        dinv[i] = d > 0 ? rsqrtf((float)d) : 0.f;
    }
}

// multi-block scan: (1) per-block inclusive scan, (2) scan block sums, (3) add offsets
__global__ void scan_block(const int* __restrict__ deg, int* __restrict__ localscan,
                           int* __restrict__ blocksum) {
    __shared__ int s[256];
    int i = blockIdx.x * 256 + threadIdx.x;
    s[threadIdx.x] = (i < N_NODES) ? deg[i] : 0;
    __syncthreads();
    for (int off = 1; off < 256; off <<= 1) {
        int t = (threadIdx.x >= off) ? s[threadIdx.x - off] : 0;
        __syncthreads();
        s[threadIdx.x] += t;
        __syncthreads();
    }
    if (i < N_NODES) localscan[i] = s[threadIdx.x];
    if (threadIdx.x == 255) blocksum[blockIdx.x] = s[255];
}

__global__ void scan_tops(int* __restrict__ blocksum) {  // 1 block, 256 threads
    __shared__ int s[256];
    int v = (threadIdx.x < NB_SCAN) ? blocksum[threadIdx.x] : 0;
    s[threadIdx.x] = v;
    __syncthreads();
    for (int off = 1; off < 256; off <<= 1) {
        int t = (threadIdx.x >= off) ? s[threadIdx.x - off] : 0;
        __syncthreads();
        s[threadIdx.x] += t;
        __syncthreads();
    }
    if (threadIdx.x < NB_SCAN) blocksum[threadIdx.x] = s[threadIdx.x] - v;  // exclusive
}

__global__ void scan_add(const int* __restrict__ localscan, const int* __restrict__ blocksum,
                         int* __restrict__ rowptr) {
    int i = blockIdx.x * 256 + threadIdx.x;
    if (i < N_NODES) rowptr[i + 1] = localscan[i] + blocksum[blockIdx.x];
    if (i == 0) rowptr[0] = 0;
}

__global__ void fill_kernel(const int* __restrict__ row, const int* __restrict__ col,
                            const int* __restrict__ rowptr, int* __restrict__ cursor,
                            const float* __restrict__ dinv,
                            int* __restrict__ colidx, float* __restrict__ wt) {
    int e = blockIdx.x * blockDim.x + threadIdx.x;
    if (e < N_EDGES) {
        int r = row[e], c = col[e];
        int pos = rowptr[r] + atomicAdd(&cursor[r], 1);
        colidx[pos] = c;
        wt[pos] = dinv[c];
    }
}

// ---------------- weight transpose (Wt[k][j] = W[j][k]) ----------------

__global__ void transpose_w(const float* __restrict__ W, float* __restrict__ Wt) {
    int idx = blockIdx.x * blockDim.x + threadIdx.x;
    if (idx < F * F) {
        int k = idx / F, j = idx % F;
        Wt[k * F + j] = W[j * F + k];
    }
}

// ---------------- fused high-pass (+ optional BN/ReLU on input) ----------------
// out[i][j] = f(h[i][j]) - ALPHA * dinv[i] * sum_e wt[e] * f(h[colidx[e]][j])
// Unrolled 8/4-wide: batch index loads, issue independent gathers for MLP.
template <int USEBN>
__global__ __launch_bounds__(256) void hp_kernel(
        const float* __restrict__ h,
        const float* __restrict__ scale, const float* __restrict__ shift,
        const float* __restrict__ dinv, const int* __restrict__ rowptr,
        const int* __restrict__ colidx, const float* __restrict__ wt,
        float* __restrict__ out) {
    int j = threadIdx.x & 127;
    int i = blockIdx.x * 2 + (threadIdx.x >> 7);
    float sc = 1.f, sh = 0.f;
    if (USEBN) { sc = scale[j]; sh = shift[j]; }
    int e0 = rowptr[i], e1 = rowptr[i + 1];
    float self = h[(size_t)i * F + j];
    float acc = 0.f;
    int e = e0;
    for (; e + 8 <= e1; e += 8) {
        int c0 = colidx[e],     c1 = colidx[e + 1], c2 = colidx[e + 2], c3 = colidx[e + 3];
        int c4 = colidx[e + 4], c5 = colidx[e + 5], c6 = colidx[e + 6], c7 = colidx[e + 7];
        float x0 = h[(size_t)c0 * F + j];
        float x1 = h[(size_t)c1 * F + j];
        float x2 = h[(size_t)c2 * F + j];
        float x3 = h[(size_t)c3 * F + j];
        float x4 = h[(size_t)c4 * F + j];
        float x5 = h[(size_t)c5 * F + j];
        float x6 = h[(size_t)c6 * F + j];
        float x7 = h[(size_t)c7 * F + j];
        if (USEBN) {
            x0 = fmaxf(x0 * sc + sh, 0.f); x1 = fmaxf(x1 * sc + sh, 0.f);
            x2 = fmaxf(x2 * sc + sh, 0.f); x3 = fmaxf(x3 * sc + sh, 0.f);
            x4 = fmaxf(x4 * sc + sh, 0.f); x5 = fmaxf(x5 * sc + sh, 0.f);
            x6 = fmaxf(x6 * sc + sh, 0.f); x7 = fmaxf(x7 * sc + sh, 0.f);
        }
        acc += wt[e] * x0;     acc += wt[e + 1] * x1;
        acc += wt[e + 2] * x2; acc += wt[e + 3] * x3;
        acc += wt[e + 4] * x4; acc += wt[e + 5] * x5;
        acc += wt[e + 6] * x6; acc += wt[e + 7] * x7;
    }
    for (; e + 4 <= e1; e += 4) {
        int c0 = colidx[e], c1 = colidx[e + 1], c2 = colidx[e + 2], c3 = colidx[e + 3];
        float x0 = h[(size_t)c0 * F + j];
        float x1 = h[(size_t)c1 * F + j];
        float x2 = h[(size_t)c2 * F + j];
        float x3 = h[(size_t)c3 * F + j];
        if (USEBN) {
            x0 = fmaxf(x0 * sc + sh, 0.f); x1 = fmaxf(x1 * sc + sh, 0.f);
            x2 = fmaxf(x2 * sc + sh, 0.f); x3 = fmaxf(x3 * sc + sh, 0.f);
        }
        acc += wt[e] * x0;     acc += wt[e + 1] * x1;
        acc += wt[e + 2] * x2; acc += wt[e + 3] * x3;
    }
    for (; e < e1; ++e) {
        int c = colidx[e];
        float x = h[(size_t)c * F + j];
        if (USEBN) x = fmaxf(x * sc + sh, 0.f);
        acc += wt[e] * x;
    }
    float x = USEBN ? fmaxf(self * sc + sh, 0.f) : self;
    out[(size_t)i * F + j] = x - ALPHA * dinv[i] * acc;
}

// ---------------- f32 GEMM + fused BN column stats ----------------
// out[M x 128] = A[M x 128] @ Wt(K-major) + bias; optional per-block col sum/sumsq.
template <int DOSTATS>
__global__ __launch_bounds__(256) void gemm_kernel(
        const float* __restrict__ A, const float* __restrict__ Wt,
        const float* __restrict__ bias, float* __restrict__ out,
        float* __restrict__ partial, int M) {
    __shared__ float sA[64][128];
    int tid = threadIdx.x;
    int row0 = blockIdx.x * 64;
    {
        const float4* Ag = (const float4*)A;
        float4* s4 = (float4*)&sA[0][0];
        for (int t = tid; t < 64 * 32; t += 256) {
            int r = row0 + (t >> 5);
            s4[t] = (r < M) ? Ag[(size_t)r * 32 + (t & 31)]
                            : make_float4(0.f, 0.f, 0.f, 0.f);
        }
    }
    __syncthreads();
    int tx = tid & 31, ty = tid >> 5;
    float acc[8][4] = {};
    #pragma unroll 4
    for (int k = 0; k < 128; ++k) {
        float4 w = ((const float4*)(Wt + (size_t)k * F))[tx];
        #pragma unroll
        for (int r = 0; r < 8; ++r) {
            float a = sA[ty * 8 + r][k];
            acc[r][0] += a * w.x;
            acc[r][1] += a * w.y;
            acc[r][2] += a * w.z;
            acc[r][3] += a * w.w;
        }
    }
    float4 b = ((const float4*)bias)[tx];
    float ls[4] = {0.f, 0.f, 0.f, 0.f}, lq[4] = {0.f, 0.f, 0.f, 0.f};
    #pragma unroll
    for (int r = 0; r < 8; ++r) {
        int rr = row0 + ty * 8 + r;
        if (rr < M) {
            float v0 = acc[r][0] + b.x, v1 = acc[r][1] + b.y;
            float v2 = acc[r][2] + b.z, v3 = acc[r][3] + b.w;
            ((float4*)out)[(size_t)rr * 32 + tx] = make_float4(v0, v1, v2, v3);
            if (DOSTATS) {
                ls[0] += v0; ls[1] += v1; ls[2] += v2; ls[3] += v3;
                lq[0] += v0 * v0; lq[1] += v1 * v1; lq[2] += v2 * v2; lq[3] += v3 * v3;
            }
        }
    }
    if (DOSTATS) {
        float* sred = &sA[0][0];  // reuse LDS
        __syncthreads();          // all sA reads done
        #pragma unroll
        for (int c = 0; c < 4; ++c) sred[ty * 128 + tx * 4 + c] = ls[c];
        __syncthreads();
        if (tid < 128) {
            float s = 0.f;
            #pragma unroll
            for (int r = 0; r < 8; ++r) s += sred[r * 128 + tid];
            partial[(size_t)blockIdx.x * 256 + tid] = s;
        }
        __syncthreads();
        #pragma unroll
        for (int c = 0; c < 4; ++c) sred[ty * 128 + tx * 4 + c] = lq[c];
        __syncthreads();
        if (tid < 128) {
            float s = 0.f;
            #pragma unroll
            for (int r = 0; r < 8; ++r) s += sred[r * 128 + tid];
            partial[(size_t)blockIdx.x * 256 + 128 + tid] = s;
        }
    }
}

__global__ void finalize_kernel(const float* __restrict__ partial,
                                const float* __restrict__ g, const float* __restrict__ bt,
                                float* __restrict__ scale, float* __restrict__ shift) {
    int j = threadIdx.x;  // 128
    float s = 0.f, sq = 0.f;
    for (int b = 0; b < GEMM_NBLK; ++b) {
        s += partial[(size_t)b * 256 + j];
        sq += partial[(size_t)b * 256 + 128 + j];
    }
    float m = s / (float)N_NODES;
    float v = sq / (float)N_NODES - m * m;
    float sc = g[j] * rsqrtf(v + BN_EPS);
    scale[j] = sc;
    shift[j] = bt[j] - m * sc;
}

// ---------------- launch ----------------

extern "C" void kernel_launch(void* const* d_in, const int* in_sizes, int n_in,
                              void* d_out, int out_size, void* d_ws, size_t ws_size,
                              hipStream_t stream) {
    const float* x   = (const float*)d_in[0];
    const int*   ei  = (const int*)d_in[1];
    const float* W1  = (const float*)d_in[2];
    const float* b1  = (const float*)d_in[3];
    const float* W2  = (const float*)d_in[4];
    const float* b2  = (const float*)d_in[5];
    const float* W3  = (const float*)d_in[6];
    const float* b3  = (const float*)d_in[7];
    const float* g1  = (const float*)d_in[8];
    const float* bt1 = (const float*)d_in[9];
    const float* g2  = (const float*)d_in[10];
    const float* bt2 = (const float*)d_in[11];
    float* out = (float*)d_out;

    const int* row = ei;
    const int* col = ei + N_EDGES;

    char* ws = (char*)d_ws;
    size_t off = 0;
    auto alloc = [&](size_t bytes) -> void* {
        void* p = ws + off;
        off += (bytes + 255) & ~(size_t)255;
        return p;
    };
    int*   deg      = (int*)alloc(N_NODES * 4);
    int*   cursor   = (int*)alloc(N_NODES * 4);
    size_t zero_bytes = off;  // only deg+cursor need zeroing
    int*   rowptr   = (int*)alloc((N_NODES + 1) * 4);
    int*   localscan= (int*)alloc(N_NODES * 4);
    int*   blocksum = (int*)alloc(NB_SCAN * 4);
    float* dinv     = (float*)alloc(N_NODES * 4);
    int*   colidx   = (int*)alloc((size_t)N_EDGES * 4);
    float* wt       = (float*)alloc((size_t)N_EDGES * 4);
    float* Wt1      = (float*)alloc(F * F * 4);
    float* Wt2      = (float*)alloc(F * F * 4);
    float* Wt3      = (float*)alloc(F * F * 4);
    float* partial  = (float*)alloc((size_t)GEMM_NBLK * 256 * 4);
    float* scale1   = (float*)alloc(F * 4);
    float* shift1   = (float*)alloc(F * 4);
    float* scale2   = (float*)alloc(F * 4);
    float* shift2   = (float*)alloc(F * 4);
    float* hp       = (float*)alloc((size_t)N_NODES * F * 4);
    (void)ws_size; (void)n_in; (void)in_sizes; (void)out_size;

    hipMemsetAsync(d_ws, 0, zero_bytes, stream);

    transpose_w<<<(F * F + 255) / 256, 256, 0, stream>>>(W1, Wt1);
    transpose_w<<<(F * F + 255) / 256, 256, 0, stream>>>(W2, Wt2);
    transpose_w<<<(F * F + 255) / 256, 256, 0, stream>>>(W3, Wt3);

    deg_kernel<<<(N_EDGES + 255) / 256, 256, 0, stream>>>(row, deg);
    dinv_kernel<<<(N_NODES + 255) / 256, 256, 0, stream>>>(deg, dinv);
    scan_block<<<NB_SCAN, 256, 0, stream>>>(deg, localscan, blocksum);
    scan_tops<<<1, 256, 0, stream>>>(blocksum);
    scan_add<<<NB_SCAN, 256, 0, stream>>>(localscan, blocksum, rowptr);
    fill_kernel<<<(N_EDGES + 255) / 256, 256, 0, stream>>>(row, col, rowptr, cursor,
                                                           dinv, colidx, wt);

    const int hp_grid = N_NODES / 2;  // 2 rows per 256-thread block

    // layer 0
    hp_kernel<0><<<hp_grid, 256, 0, stream>>>(x, nullptr, nullptr, dinv, rowptr,
                                              colidx, wt, hp);
    gemm_kernel<1><<<GEMM_NBLK, 256, 0, stream>>>(hp, Wt1, b1, out, partial, N_NODES);
    finalize_kernel<<<1, 128, 0, stream>>>(partial, g1, bt1, scale1, shift1);

    // layer 1
    hp_kernel<1><<<hp_grid, 256, 0, stream>>>(out, scale1, shift1, dinv, rowptr,
                                              colidx, wt, hp);
    gemm_kernel<1><<<GEMM_NBLK, 256, 0, stream>>>(hp, Wt2, b2, out, partial, N_NODES);
    finalize_kernel<<<1, 128, 0, stream>>>(partial, g2, bt2, scale2, shift2);

    // layer 2 (output)
    hp_kernel<1><<<hp_grid, 256, 0, stream>>>(out, scale2, shift2, dinv, rowptr,
                                              colidx, wt, hp);
    gemm_kernel<0><<<GEMM_NBLK, 256, 0, stream>>>(hp, Wt3, b3, out, nullptr, N_NODES);
}

// Round 3
// 400.745 us; speedup vs baseline: 2.1089x; 1.5093x over previous
//
#include <hip/hip_runtime.h>

#define N_NODES 50000
#define N_EDGES 800000
#define F 128
#define ALPHA 0.5f
#define BN_EPS 1e-5f
#define NB_SCAN ((N_NODES + 255) / 256)   // 196
#define GEMM_NBLK ((N_NODES + 63) / 64)   // 782

// ---------------- CSR build ----------------

__global__ void deg_kernel(const int* __restrict__ row, int* __restrict__ deg) {
    int e = blockIdx.x * blockDim.x + threadIdx.x;
    if (e < N_EDGES) atomicAdd(&deg[row[e]], 1);
}

__global__ void dinv_kernel(const int* __restrict__ deg, float* __restrict__ dinv) {
    int i = blockIdx.x * blockDim.x + threadIdx.x;
    if (i < N_NODES) {
        int d = deg[i];
        dinv[i] = d > 0 ? rsqrtf((float)d) : 0.f;
    }
}

// multi-block scan: (1) per-block inclusive scan, (2) scan block sums, (3) add offsets
__global__ void scan_block(const int* __restrict__ deg, int* __restrict__ localscan,
                           int* __restrict__ blocksum) {
    __shared__ int s[256];
    int i = blockIdx.x * 256 + threadIdx.x;
    s[threadIdx.x] = (i < N_NODES) ? deg[i] : 0;
    __syncthreads();
    for (int off = 1; off < 256; off <<= 1) {
        int t = (threadIdx.x >= off) ? s[threadIdx.x - off] : 0;
        __syncthreads();
        s[threadIdx.x] += t;
        __syncthreads();
    }
    if (i < N_NODES) localscan[i] = s[threadIdx.x];
    if (threadIdx.x == 255) blocksum[blockIdx.x] = s[255];
}

__global__ void scan_tops(int* __restrict__ blocksum) {  // 1 block, 256 threads
    __shared__ int s[256];
    int v = (threadIdx.x < NB_SCAN) ? blocksum[threadIdx.x] : 0;
    s[threadIdx.x] = v;
    __syncthreads();
    for (int off = 1; off < 256; off <<= 1) {
        int t = (threadIdx.x >= off) ? s[threadIdx.x - off] : 0;
        __syncthreads();
        s[threadIdx.x] += t;
        __syncthreads();
    }
    if (threadIdx.x < NB_SCAN) blocksum[threadIdx.x] = s[threadIdx.x] - v;  // exclusive
}

__global__ void scan_add(const int* __restrict__ localscan, const int* __restrict__ blocksum,
                         int* __restrict__ rowptr) {
    int i = blockIdx.x * 256 + threadIdx.x;
    if (i < N_NODES) rowptr[i + 1] = localscan[i] + blocksum[blockIdx.x];
    if (i == 0) rowptr[0] = 0;
}

__global__ void fill_kernel(const int* __restrict__ row, const int* __restrict__ col,
                            const int* __restrict__ rowptr, int* __restrict__ cursor,
                            const float* __restrict__ dinv,
                            int* __restrict__ colidx, float* __restrict__ wt) {
    int e = blockIdx.x * blockDim.x + threadIdx.x;
    if (e < N_EDGES) {
        int r = row[e], c = col[e];
        int pos = rowptr[r] + atomicAdd(&cursor[r], 1);
        colidx[pos] = c;
        wt[pos] = dinv[c];
    }
}

// ---------------- weight transpose (Wt[k][j] = W[j][k]) ----------------

__global__ void transpose_w(const float* __restrict__ W, float* __restrict__ Wt) {
    int idx = blockIdx.x * blockDim.x + threadIdx.x;
    if (idx < F * F) {
        int k = idx / F, j = idx % F;
        Wt[k * F + j] = W[j * F + k];
    }
}

// ---------------- fused high-pass (+ optional BN/ReLU on input) ----------------
// out[i][j] = f(h[i][j]) - ALPHA * dinv[i] * sum_e wt[e] * f(h[colidx[e]][j])
template <int USEBN>
__global__ __launch_bounds__(256) void hp_kernel(
        const float* __restrict__ h,
        const float* __restrict__ scale, const float* __restrict__ shift,
        const float* __restrict__ dinv, const int* __restrict__ rowptr,
        const int* __restrict__ colidx, const float* __restrict__ wt,
        float* __restrict__ out) {
    int j = threadIdx.x & 127;
    int i = blockIdx.x * 2 + (threadIdx.x >> 7);
    float sc = 1.f, sh = 0.f;
    if (USEBN) { sc = scale[j]; sh = shift[j]; }
    int e0 = rowptr[i], e1 = rowptr[i + 1];
    float self = h[(size_t)i * F + j];
    float acc = 0.f;
    int e = e0;
    for (; e + 8 <= e1; e += 8) {
        int c0 = colidx[e],     c1 = colidx[e + 1], c2 = colidx[e + 2], c3 = colidx[e + 3];
        int c4 = colidx[e + 4], c5 = colidx[e + 5], c6 = colidx[e + 6], c7 = colidx[e + 7];
        float x0 = h[(size_t)c0 * F + j];
        float x1 = h[(size_t)c1 * F + j];
        float x2 = h[(size_t)c2 * F + j];
        float x3 = h[(size_t)c3 * F + j];
        float x4 = h[(size_t)c4 * F + j];
        float x5 = h[(size_t)c5 * F + j];
        float x6 = h[(size_t)c6 * F + j];
        float x7 = h[(size_t)c7 * F + j];
        if (USEBN) {
            x0 = fmaxf(x0 * sc + sh, 0.f); x1 = fmaxf(x1 * sc + sh, 0.f);
            x2 = fmaxf(x2 * sc + sh, 0.f); x3 = fmaxf(x3 * sc + sh, 0.f);
            x4 = fmaxf(x4 * sc + sh, 0.f); x5 = fmaxf(x5 * sc + sh, 0.f);
            x6 = fmaxf(x6 * sc + sh, 0.f); x7 = fmaxf(x7 * sc + sh, 0.f);
        }
        acc += wt[e] * x0;     acc += wt[e + 1] * x1;
        acc += wt[e + 2] * x2; acc += wt[e + 3] * x3;
        acc += wt[e + 4] * x4; acc += wt[e + 5] * x5;
        acc += wt[e + 6] * x6; acc += wt[e + 7] * x7;
    }
    for (; e + 4 <= e1; e += 4) {
        int c0 = colidx[e], c1 = colidx[e + 1], c2 = colidx[e + 2], c3 = colidx[e + 3];
        float x0 = h[(size_t)c0 * F + j];
        float x1 = h[(size_t)c1 * F + j];
        float x2 = h[(size_t)c2 * F + j];
        float x3 = h[(size_t)c3 * F + j];
        if (USEBN) {
            x0 = fmaxf(x0 * sc + sh, 0.f); x1 = fmaxf(x1 * sc + sh, 0.f);
            x2 = fmaxf(x2 * sc + sh, 0.f); x3 = fmaxf(x3 * sc + sh, 0.f);
        }
        acc += wt[e] * x0;     acc += wt[e + 1] * x1;
        acc += wt[e + 2] * x2; acc += wt[e + 3] * x3;
    }
    for (; e < e1; ++e) {
        int c = colidx[e];
        float x = h[(size_t)c * F + j];
        if (USEBN) x = fmaxf(x * sc + sh, 0.f);
        acc += wt[e] * x;
    }
    float x = USEBN ? fmaxf(self * sc + sh, 0.f) : self;
    out[(size_t)i * F + j] = x - ALPHA * dinv[i] * acc;
}

// ---------------- f32 GEMM + fused BN column partials ----------------
template <int DOSTATS>
__global__ __launch_bounds__(256) void gemm_kernel(
        const float* __restrict__ A, const float* __restrict__ Wt,
        const float* __restrict__ bias, float* __restrict__ out,
        float* __restrict__ partial, int M) {
    __shared__ float sA[64][128];
    int tid = threadIdx.x;
    int row0 = blockIdx.x * 64;
    {
        const float4* Ag = (const float4*)A;
        float4* s4 = (float4*)&sA[0][0];
        for (int t = tid; t < 64 * 32; t += 256) {
            int r = row0 + (t >> 5);
            s4[t] = (r < M) ? Ag[(size_t)r * 32 + (t & 31)]
                            : make_float4(0.f, 0.f, 0.f, 0.f);
        }
    }
    __syncthreads();
    int tx = tid & 31, ty = tid >> 5;
    float acc[8][4] = {};
    #pragma unroll 4
    for (int k = 0; k < 128; ++k) {
        float4 w = ((const float4*)(Wt + (size_t)k * F))[tx];
        #pragma unroll
        for (int r = 0; r < 8; ++r) {
            float a = sA[ty * 8 + r][k];
            acc[r][0] += a * w.x;
            acc[r][1] += a * w.y;
            acc[r][2] += a * w.z;
            acc[r][3] += a * w.w;
        }
    }
    float4 b = ((const float4*)bias)[tx];
    float ls[4] = {0.f, 0.f, 0.f, 0.f}, lq[4] = {0.f, 0.f, 0.f, 0.f};
    #pragma unroll
    for (int r = 0; r < 8; ++r) {
        int rr = row0 + ty * 8 + r;
        if (rr < M) {
            float v0 = acc[r][0] + b.x, v1 = acc[r][1] + b.y;
            float v2 = acc[r][2] + b.z, v3 = acc[r][3] + b.w;
            ((float4*)out)[(size_t)rr * 32 + tx] = make_float4(v0, v1, v2, v3);
            if (DOSTATS) {
                ls[0] += v0; ls[1] += v1; ls[2] += v2; ls[3] += v3;
                lq[0] += v0 * v0; lq[1] += v1 * v1; lq[2] += v2 * v2; lq[3] += v3 * v3;
            }
        }
    }
    if (DOSTATS) {
        float* sred = &sA[0][0];  // reuse LDS
        __syncthreads();          // all sA reads done
        #pragma unroll
        for (int c = 0; c < 4; ++c) sred[ty * 128 + tx * 4 + c] = ls[c];
        __syncthreads();
        if (tid < 128) {
            float s = 0.f;
            #pragma unroll
            for (int r = 0; r < 8; ++r) s += sred[r * 128 + tid];
            partial[(size_t)blockIdx.x * 256 + tid] = s;
        }
        __syncthreads();
        #pragma unroll
        for (int c = 0; c < 4; ++c) sred[ty * 128 + tx * 4 + c] = lq[c];
        __syncthreads();
        if (tid < 128) {
            float s = 0.f;
            #pragma unroll
            for (int r = 0; r < 8; ++r) s += sred[r * 128 + tid];
            partial[(size_t)blockIdx.x * 256 + 128 + tid] = s;
        }
    }
}

// ---------------- BN reduce: 128 blocks, one column each ----------------
// block j: sum partial[b*256+j] (colsum) and partial[b*256+128+j] (colsumsq)
// over b in [0, GEMM_NBLK); thread 0 writes scale[j], shift[j].
__global__ __launch_bounds__(256) void bn_reduce_kernel(
        const float* __restrict__ partial,
        const float* __restrict__ g, const float* __restrict__ bt,
        float* __restrict__ scale, float* __restrict__ shift) {
    __shared__ float ss[256], sq[256];
    int j = blockIdx.x;       // 0..127
    int tid = threadIdx.x;    // 0..255
    float s = 0.f, q = 0.f;
    for (int b = tid; b < GEMM_NBLK; b += 256) {
        s += partial[(size_t)b * 256 + j];
        q += partial[(size_t)b * 256 + 128 + j];
    }
    ss[tid] = s; sq[tid] = q;
    __syncthreads();
    for (int off = 128; off > 0; off >>= 1) {
        if (tid < off) { ss[tid] += ss[tid + off]; sq[tid] += sq[tid + off]; }
        __syncthreads();
    }
    if (tid == 0) {
        float m = ss[0] / (float)N_NODES;
        float v = sq[0] / (float)N_NODES - m * m;
        float sc = g[j] * rsqrtf(v + BN_EPS);
        scale[j] = sc;
        shift[j] = bt[j] - m * sc;
    }
}

// ---------------- launch ----------------

extern "C" void kernel_launch(void* const* d_in, const int* in_sizes, int n_in,
                              void* d_out, int out_size, void* d_ws, size_t ws_size,
                              hipStream_t stream) {
    const float* x   = (const float*)d_in[0];
    const int*   ei  = (const int*)d_in[1];
    const float* W1  = (const float*)d_in[2];
    const float* b1  = (const float*)d_in[3];
    const float* W2  = (const float*)d_in[4];
    const float* b2  = (const float*)d_in[5];
    const float* W3  = (const float*)d_in[6];
    const float* b3  = (const float*)d_in[7];
    const float* g1  = (const float*)d_in[8];
    const float* bt1 = (const float*)d_in[9];
    const float* g2  = (const float*)d_in[10];
    const float* bt2 = (const float*)d_in[11];
    float* out = (float*)d_out;

    const int* row = ei;
    const int* col = ei + N_EDGES;

    char* ws = (char*)d_ws;
    size_t off = 0;
    auto alloc = [&](size_t bytes) -> void* {
        void* p = ws + off;
        off += (bytes + 255) & ~(size_t)255;
        return p;
    };
    int*   deg      = (int*)alloc(N_NODES * 4);
    int*   cursor   = (int*)alloc(N_NODES * 4);
    size_t zero_bytes = off;  // only deg+cursor need zeroing
    int*   rowptr   = (int*)alloc((N_NODES + 1) * 4);
    int*   localscan= (int*)alloc(N_NODES * 4);
    int*   blocksum = (int*)alloc(NB_SCAN * 4);
    float* dinv     = (float*)alloc(N_NODES * 4);
    int*   colidx   = (int*)alloc((size_t)N_EDGES * 4);
    float* wt       = (float*)alloc((size_t)N_EDGES * 4);
    float* Wt1      = (float*)alloc(F * F * 4);
    float* Wt2      = (float*)alloc(F * F * 4);
    float* Wt3      = (float*)alloc(F * F * 4);
    float* partial  = (float*)alloc((size_t)GEMM_NBLK * 256 * 4);
    float* scale1   = (float*)alloc(F * 4);
    float* shift1   = (float*)alloc(F * 4);
    float* scale2   = (float*)alloc(F * 4);
    float* shift2   = (float*)alloc(F * 4);
    float* hp       = (float*)alloc((size_t)N_NODES * F * 4);
    (void)ws_size; (void)n_in; (void)in_sizes; (void)out_size;

    hipMemsetAsync(d_ws, 0, zero_bytes, stream);

    transpose_w<<<(F * F + 255) / 256, 256, 0, stream>>>(W1, Wt1);
    transpose_w<<<(F * F + 255) / 256, 256, 0, stream>>>(W2, Wt2);
    transpose_w<<<(F * F + 255) / 256, 256, 0, stream>>>(W3, Wt3);

    deg_kernel<<<(N_EDGES + 255) / 256, 256, 0, stream>>>(row, deg);
    dinv_kernel<<<(N_NODES + 255) / 256, 256, 0, stream>>>(deg, dinv);
    scan_block<<<NB_SCAN, 256, 0, stream>>>(deg, localscan, blocksum);
    scan_tops<<<1, 256, 0, stream>>>(blocksum);
    scan_add<<<NB_SCAN, 256, 0, stream>>>(localscan, blocksum, rowptr);
    fill_kernel<<<(N_EDGES + 255) / 256, 256, 0, stream>>>(row, col, rowptr, cursor,
                                                           dinv, colidx, wt);

    const int hp_grid = N_NODES / 2;  // 2 rows per 256-thread block

    // layer 0
    hp_kernel<0><<<hp_grid, 256, 0, stream>>>(x, nullptr, nullptr, dinv, rowptr,
                                              colidx, wt, hp);
    gemm_kernel<1><<<GEMM_NBLK, 256, 0, stream>>>(hp, Wt1, b1, out, partial, N_NODES);
    bn_reduce_kernel<<<128, 256, 0, stream>>>(partial, g1, bt1, scale1, shift1);

    // layer 1
    hp_kernel<1><<<hp_grid, 256, 0, stream>>>(out, scale1, shift1, dinv, rowptr,
                                              colidx, wt, hp);
    gemm_kernel<1><<<GEMM_NBLK, 256, 0, stream>>>(hp, Wt2, b2, out, partial, N_NODES);
    bn_reduce_kernel<<<128, 256, 0, stream>>>(partial, g2, bt2, scale2, shift2);

    // layer 2 (output)
    hp_kernel<1><<<hp_grid, 256, 0, stream>>>(out, scale2, shift2, dinv, rowptr,
                                              colidx, wt, hp);
    gemm_kernel<0><<<GEMM_NBLK, 256, 0, stream>>>(hp, Wt3, b3, out, nullptr, N_NODES);
}

// Round 5
// 384.873 us; speedup vs baseline: 2.1959x; 1.0412x over previous
//
#include <hip/hip_runtime.h>

#define N_NODES 50000
#define N_EDGES 800000
#define F 128
#define ALPHA 0.5f
#define BN_EPS 1e-5f
#define NB_SCAN ((N_NODES + 255) / 256)   // 196
#define GEMM_NBLK ((N_NODES + 63) / 64)   // 782

// ---------------- CSR build ----------------

__global__ void deg_kernel(const int* __restrict__ row, int* __restrict__ deg) {
    int e = blockIdx.x * blockDim.x + threadIdx.x;
    if (e < N_EDGES) atomicAdd(&deg[row[e]], 1);
}

// per-block inclusive scan; also emits dinv = deg^-1/2
__global__ void scan_block(const int* __restrict__ deg, int* __restrict__ localscan,
                           int* __restrict__ blocksum, float* __restrict__ dinv) {
    __shared__ int s[256];
    int i = blockIdx.x * 256 + threadIdx.x;
    int v = (i < N_NODES) ? deg[i] : 0;
    if (i < N_NODES) dinv[i] = v > 0 ? rsqrtf((float)v) : 0.f;
    s[threadIdx.x] = v;
    __syncthreads();
    for (int off = 1; off < 256; off <<= 1) {
        int t = (threadIdx.x >= off) ? s[threadIdx.x - off] : 0;
        __syncthreads();
        s[threadIdx.x] += t;
        __syncthreads();
    }
    if (i < N_NODES) localscan[i] = s[threadIdx.x];
    if (threadIdx.x == 255) blocksum[blockIdx.x] = s[255];
}

__global__ void scan_tops(int* __restrict__ blocksum) {  // 1 block, 256 threads
    __shared__ int s[256];
    int v = (threadIdx.x < NB_SCAN) ? blocksum[threadIdx.x] : 0;
    s[threadIdx.x] = v;
    __syncthreads();
    for (int off = 1; off < 256; off <<= 1) {
        int t = (threadIdx.x >= off) ? s[threadIdx.x - off] : 0;
        __syncthreads();
        s[threadIdx.x] += t;
        __syncthreads();
    }
    if (threadIdx.x < NB_SCAN) blocksum[threadIdx.x] = s[threadIdx.x] - v;  // exclusive
}

__global__ void scan_add(const int* __restrict__ localscan, const int* __restrict__ blocksum,
                         int* __restrict__ rowptr) {
    int i = blockIdx.x * 256 + threadIdx.x;
    if (i < N_NODES) rowptr[i + 1] = localscan[i] + blocksum[blockIdx.x];
    if (i == 0) rowptr[0] = 0;
}

// packed edge record: {col * 512 (byte offset of row), bitcast(dinv[col])}
__global__ void fill_kernel(const int* __restrict__ row, const int* __restrict__ col,
                            const int* __restrict__ rowptr, int* __restrict__ cursor,
                            const float* __restrict__ dinv,
                            int2* __restrict__ colwt) {
    int e = blockIdx.x * blockDim.x + threadIdx.x;
    if (e < N_EDGES) {
        int r = row[e], c = col[e];
        int pos = rowptr[r] + atomicAdd(&cursor[r], 1);
        colwt[pos] = make_int2(c * (F * 4), __float_as_int(dinv[c]));
    }
}

// ---------------- weight transposes (all three in one kernel) ----------------

__global__ void transpose_w3(const float* __restrict__ W1, const float* __restrict__ W2,
                             const float* __restrict__ W3, float* __restrict__ Wt1,
                             float* __restrict__ Wt2, float* __restrict__ Wt3) {
    int idx = blockIdx.x * 256 + threadIdx.x;   // 3 * 16384
    int which = idx >> 14;
    int r = idx & 16383;
    const float* W = (which == 0) ? W1 : (which == 1) ? W2 : W3;
    float* Wt = (which == 0) ? Wt1 : (which == 1) ? Wt2 : Wt3;
    int k = r >> 7, j = r & 127;
    Wt[k * F + j] = W[j * F + k];
}

// ---------------- fused high-pass, wave-per-row, float4 gathers ----------------

__device__ __forceinline__ float4 bn_relu4(float4 v, float4 sc, float4 sh) {
    v.x = fmaxf(fmaf(v.x, sc.x, sh.x), 0.f);
    v.y = fmaxf(fmaf(v.y, sc.y, sh.y), 0.f);
    v.z = fmaxf(fmaf(v.z, sc.z, sh.z), 0.f);
    v.w = fmaxf(fmaf(v.w, sc.w, sh.w), 0.f);
    return v;
}

__device__ __forceinline__ void accum4(float4& a, float w, float4 v) {
    a.x = fmaf(w, v.x, a.x);
    a.y = fmaf(w, v.y, a.y);
    a.z = fmaf(w, v.z, a.z);
    a.w = fmaf(w, v.w, a.w);
}

// out[i][:] = f(h[i][:]) - ALPHA*dinv[i]*sum_e w_e * f(h[col_e][:])
// wave = 64 lanes: lane (l = lane&31) owns cols l*4..l*4+3; half 0 takes even
// edges, half 1 odd edges; halves combined via shfl_xor(32).
template <int USEBN>
__global__ __launch_bounds__(256) void hp_kernel(
        const float* __restrict__ h,
        const float* __restrict__ scale, const float* __restrict__ shift,
        const float* __restrict__ dinv, const int* __restrict__ rowptr,
        const int2* __restrict__ colwt, float* __restrict__ out) {
    int lane = threadIdx.x & 63;
    int half = lane >> 5;
    int l = lane & 31;
    int i = blockIdx.x * 4 + (threadIdx.x >> 6);   // 4 waves per block, 1 row each

    float4 sc4 = make_float4(1.f, 1.f, 1.f, 1.f);
    float4 sh4 = make_float4(0.f, 0.f, 0.f, 0.f);
    if (USEBN) { sc4 = ((const float4*)scale)[l]; sh4 = ((const float4*)shift)[l]; }

    int e0 = rowptr[i], e1 = rowptr[i + 1];
    const char* hb = (const char*)h;
    int loff = l * 16;

    float4 acc = make_float4(0.f, 0.f, 0.f, 0.f);

    int e = e0 + half;
    for (; e + 6 < e1; e += 8) {   // 4 edges per half per iter
        int2 cw0 = colwt[e];
        int2 cw1 = colwt[e + 2];
        int2 cw2 = colwt[e + 4];
        int2 cw3 = colwt[e + 6];
        float4 v0 = *(const float4*)(hb + (size_t)(cw0.x + loff));
        float4 v1 = *(const float4*)(hb + (size_t)(cw1.x + loff));
        float4 v2 = *(const float4*)(hb + (size_t)(cw2.x + loff));
        float4 v3 = *(const float4*)(hb + (size_t)(cw3.x + loff));
        if (USEBN) {
            v0 = bn_relu4(v0, sc4, sh4);
            v1 = bn_relu4(v1, sc4, sh4);
            v2 = bn_relu4(v2, sc4, sh4);
            v3 = bn_relu4(v3, sc4, sh4);
        }
        accum4(acc, __int_as_float(cw0.y), v0);
        accum4(acc, __int_as_float(cw1.y), v1);
        accum4(acc, __int_as_float(cw2.y), v2);
        accum4(acc, __int_as_float(cw3.y), v3);
    }
    for (; e < e1; e += 2) {
        int2 cw = colwt[e];
        float4 v = *(const float4*)(hb + (size_t)(cw.x + loff));
        if (USEBN) v = bn_relu4(v, sc4, sh4);
        accum4(acc, __int_as_float(cw.y), v);
    }

    // combine the two halves
    acc.x += __shfl_xor(acc.x, 32);
    acc.y += __shfl_xor(acc.y, 32);
    acc.z += __shfl_xor(acc.z, 32);
    acc.w += __shfl_xor(acc.w, 32);

    float4 self = ((const float4*)h)[(size_t)i * 32 + l];
    if (USEBN) self = bn_relu4(self, sc4, sh4);
    float a = ALPHA * dinv[i];
    if (half == 0) {
        float4 res = make_float4(self.x - a * acc.x, self.y - a * acc.y,
                                 self.z - a * acc.z, self.w - a * acc.w);
        ((float4*)out)[(size_t)i * 32 + l] = res;
    }
}

// ---------------- f32 GEMM + fused BN column partials ----------------
template <int DOSTATS>
__global__ __launch_bounds__(256) void gemm_kernel(
        const float* __restrict__ A, const float* __restrict__ Wt,
        const float* __restrict__ bias, float* __restrict__ out,
        float* __restrict__ partial, int M) {
    __shared__ float sA[64][128];
    int tid = threadIdx.x;
    int row0 = blockIdx.x * 64;
    {
        const float4* Ag = (const float4*)A;
        float4* s4 = (float4*)&sA[0][0];
        for (int t = tid; t < 64 * 32; t += 256) {
            int r = row0 + (t >> 5);
            s4[t] = (r < M) ? Ag[(size_t)r * 32 + (t & 31)]
                            : make_float4(0.f, 0.f, 0.f, 0.f);
        }
    }
    __syncthreads();
    int tx = tid & 31, ty = tid >> 5;
    float acc[8][4] = {};
    for (int k = 0; k < 128; k += 4) {
        float4 w0 = ((const float4*)(Wt + (size_t)k * F))[tx];
        float4 w1 = ((const float4*)(Wt + (size_t)(k + 1) * F))[tx];
        float4 w2 = ((const float4*)(Wt + (size_t)(k + 2) * F))[tx];
        float4 w3 = ((const float4*)(Wt + (size_t)(k + 3) * F))[tx];
        #pragma unroll
        for (int r = 0; r < 8; ++r) {
            float4 a = *(const float4*)&sA[ty * 8 + r][k];
            acc[r][0] += a.x * w0.x + a.y * w1.x + a.z * w2.x + a.w * w3.x;
            acc[r][1] += a.x * w0.y + a.y * w1.y + a.z * w2.y + a.w * w3.y;
            acc[r][2] += a.x * w0.z + a.y * w1.z + a.z * w2.z + a.w * w3.z;
            acc[r][3] += a.x * w0.w + a.y * w1.w + a.z * w2.w + a.w * w3.w;
        }
    }
    float4 b = ((const float4*)bias)[tx];
    float ls[4] = {0.f, 0.f, 0.f, 0.f}, lq[4] = {0.f, 0.f, 0.f, 0.f};
    #pragma unroll
    for (int r = 0; r < 8; ++r) {
        int rr = row0 + ty * 8 + r;
        if (rr < M) {
            float v0 = acc[r][0] + b.x, v1 = acc[r][1] + b.y;
            float v2 = acc[r][2] + b.z, v3 = acc[r][3] + b.w;
            ((float4*)out)[(size_t)rr * 32 + tx] = make_float4(v0, v1, v2, v3);
            if (DOSTATS) {
                ls[0] += v0; ls[1] += v1; ls[2] += v2; ls[3] += v3;
                lq[0] += v0 * v0; lq[1] += v1 * v1; lq[2] += v2 * v2; lq[3] += v3 * v3;
            }
        }
    }
    if (DOSTATS) {
        float* sred = &sA[0][0];  // reuse LDS
        __syncthreads();          // all sA reads done
        #pragma unroll
        for (int c = 0; c < 4; ++c) sred[ty * 128 + tx * 4 + c] = ls[c];
        __syncthreads();
        if (tid < 128) {
            float s = 0.f;
            #pragma unroll
            for (int r = 0; r < 8; ++r) s += sred[r * 128 + tid];
            partial[(size_t)blockIdx.x * 256 + tid] = s;
        }
        __syncthreads();
        #pragma unroll
        for (int c = 0; c < 4; ++c) sred[ty * 128 + tx * 4 + c] = lq[c];
        __syncthreads();
        if (tid < 128) {
            float s = 0.f;
            #pragma unroll
            for (int r = 0; r < 8; ++r) s += sred[r * 128 + tid];
            partial[(size_t)blockIdx.x * 256 + 128 + tid] = s;
        }
    }
}

// ---------------- BN reduce: 128 blocks, one column each ----------------
__global__ __launch_bounds__(256) void bn_reduce_kernel(
        const float* __restrict__ partial,
        const float* __restrict__ g, const float* __restrict__ bt,
        float* __restrict__ scale, float* __restrict__ shift) {
    __shared__ float ss[256], sq[256];
    int j = blockIdx.x;       // 0..127
    int tid = threadIdx.x;    // 0..255
    float s = 0.f, q = 0.f;
    for (int b = tid; b < GEMM_NBLK; b += 256) {
        s += partial[(size_t)b * 256 + j];
        q += partial[(size_t)b * 256 + 128 + j];
    }
    ss[tid] = s; sq[tid] = q;
    __syncthreads();
    for (int off = 128; off > 0; off >>= 1) {
        if (tid < off) { ss[tid] += ss[tid + off]; sq[tid] += sq[tid + off]; }
        __syncthreads();
    }
    if (tid == 0) {
        float m = ss[0] / (float)N_NODES;
        float v = sq[0] / (float)N_NODES - m * m;
        float sc = g[j] * rsqrtf(v + BN_EPS);
        scale[j] = sc;
        shift[j] = bt[j] - m * sc;
    }
}

// ---------------- launch ----------------

extern "C" void kernel_launch(void* const* d_in, const int* in_sizes, int n_in,
                              void* d_out, int out_size, void* d_ws, size_t ws_size,
                              hipStream_t stream) {
    const float* x   = (const float*)d_in[0];
    const int*   ei  = (const int*)d_in[1];
    const float* W1  = (const float*)d_in[2];
    const float* b1  = (const float*)d_in[3];
    const float* W2  = (const float*)d_in[4];
    const float* b2  = (const float*)d_in[5];
    const float* W3  = (const float*)d_in[6];
    const float* b3  = (const float*)d_in[7];
    const float* g1  = (const float*)d_in[8];
    const float* bt1 = (const float*)d_in[9];
    const float* g2  = (const float*)d_in[10];
    const float* bt2 = (const float*)d_in[11];
    float* out = (float*)d_out;

    const int* row = ei;
    const int* col = ei + N_EDGES;

    char* ws = (char*)d_ws;
    size_t off = 0;
    auto alloc = [&](size_t bytes) -> void* {
        void* p = ws + off;
        off += (bytes + 255) & ~(size_t)255;
        return p;
    };
    int*   deg      = (int*)alloc(N_NODES * 4);
    int*   cursor   = (int*)alloc(N_NODES * 4);
    size_t zero_bytes = off;  // only deg+cursor need zeroing
    int*   rowptr   = (int*)alloc((N_NODES + 1) * 4);
    int*   localscan= (int*)alloc(N_NODES * 4);
    int*   blocksum = (int*)alloc(NB_SCAN * 4);
    float* dinv     = (float*)alloc(N_NODES * 4);
    int2*  colwt    = (int2*)alloc((size_t)N_EDGES * 8);
    float* Wt1      = (float*)alloc(F * F * 4);
    float* Wt2      = (float*)alloc(F * F * 4);
    float* Wt3      = (float*)alloc(F * F * 4);
    float* partial  = (float*)alloc((size_t)GEMM_NBLK * 256 * 4);
    float* scale1   = (float*)alloc(F * 4);
    float* shift1   = (float*)alloc(F * 4);
    float* scale2   = (float*)alloc(F * 4);
    float* shift2   = (float*)alloc(F * 4);
    float* hp       = (float*)alloc((size_t)N_NODES * F * 4);
    (void)ws_size; (void)n_in; (void)in_sizes; (void)out_size;

    hipMemsetAsync(d_ws, 0, zero_bytes, stream);

    transpose_w3<<<192, 256, 0, stream>>>(W1, W2, W3, Wt1, Wt2, Wt3);

    deg_kernel<<<(N_EDGES + 255) / 256, 256, 0, stream>>>(row, deg);
    scan_block<<<NB_SCAN, 256, 0, stream>>>(deg, localscan, blocksum, dinv);
    scan_tops<<<1, 256, 0, stream>>>(blocksum);
    scan_add<<<NB_SCAN, 256, 0, stream>>>(localscan, blocksum, rowptr);
    fill_kernel<<<(N_EDGES + 255) / 256, 256, 0, stream>>>(row, col, rowptr, cursor,
                                                           dinv, colwt);

    const int hp_grid = N_NODES / 4;  // 4 waves/block, 1 row per wave

    // layer 0
    hp_kernel<0><<<hp_grid, 256, 0, stream>>>(x, nullptr, nullptr, dinv, rowptr,
                                              colwt, hp);
    gemm_kernel<1><<<GEMM_NBLK, 256, 0, stream>>>(hp, Wt1, b1, out, partial, N_NODES);
    bn_reduce_kernel<<<128, 256, 0, stream>>>(partial, g1, bt1, scale1, shift1);

    // layer 1
    hp_kernel<1><<<hp_grid, 256, 0, stream>>>(out, scale1, shift1, dinv, rowptr,
                                              colwt, hp);
    gemm_kernel<1><<<GEMM_NBLK, 256, 0, stream>>>(hp, Wt2, b2, out, partial, N_NODES);
    bn_reduce_kernel<<<128, 256, 0, stream>>>(partial, g2, bt2, scale2, shift2);

    // layer 2 (output)
    hp_kernel<1><<<hp_grid, 256, 0, stream>>>(out, scale2, shift2, dinv, rowptr,
                                              colwt, hp);
    gemm_kernel<0><<<GEMM_NBLK, 256, 0, stream>>>(hp, Wt3, b3, out, nullptr, N_NODES);
}

// Round 6
// 250.533 us; speedup vs baseline: 3.3733x; 1.5362x over previous
//
#include <hip/hip_runtime.h>
#include <hip/hip_fp16.h>

#define N_NODES 50000
#define N_EDGES 800000
#define F 128
#define ALPHA 0.5f
#define BN_EPS 1e-5f
#define NB_SCAN ((N_NODES + 255) / 256)   // 196
#define GEMM_NBLK ((N_NODES + 63) / 64)   // 782

typedef _Float16 half8_t __attribute__((ext_vector_type(8)));
typedef float floatx4 __attribute__((ext_vector_type(4)));

union H8 { uint4 u; __half2 h2[4]; };

// ---------------- CSR build ----------------

__global__ void deg_kernel(const int* __restrict__ row, int* __restrict__ deg) {
    int e = blockIdx.x * blockDim.x + threadIdx.x;
    if (e < N_EDGES) atomicAdd(&deg[row[e]], 1);
}

// per-block inclusive scan; also emits dinv = deg^-1/2
__global__ void scan_block(const int* __restrict__ deg, int* __restrict__ localscan,
                           int* __restrict__ blocksum, float* __restrict__ dinv) {
    __shared__ int s[256];
    int i = blockIdx.x * 256 + threadIdx.x;
    int v = (i < N_NODES) ? deg[i] : 0;
    if (i < N_NODES) dinv[i] = v > 0 ? rsqrtf((float)v) : 0.f;
    s[threadIdx.x] = v;
    __syncthreads();
    for (int off = 1; off < 256; off <<= 1) {
        int t = (threadIdx.x >= off) ? s[threadIdx.x - off] : 0;
        __syncthreads();
        s[threadIdx.x] += t;
        __syncthreads();
    }
    if (i < N_NODES) localscan[i] = s[threadIdx.x];
    if (threadIdx.x == 255) blocksum[blockIdx.x] = s[255];
}

__global__ void scan_tops(int* __restrict__ blocksum) {  // 1 block, 256 threads
    __shared__ int s[256];
    int v = (threadIdx.x < NB_SCAN) ? blocksum[threadIdx.x] : 0;
    s[threadIdx.x] = v;
    __syncthreads();
    for (int off = 1; off < 256; off <<= 1) {
        int t = (threadIdx.x >= off) ? s[threadIdx.x - off] : 0;
        __syncthreads();
        s[threadIdx.x] += t;
        __syncthreads();
    }
    if (threadIdx.x < NB_SCAN) blocksum[threadIdx.x] = s[threadIdx.x] - v;  // exclusive
}

__global__ void scan_add(const int* __restrict__ localscan, const int* __restrict__ blocksum,
                         int* __restrict__ rowptr) {
    int i = blockIdx.x * 256 + threadIdx.x;
    if (i < N_NODES) rowptr[i + 1] = localscan[i] + blocksum[blockIdx.x];
    if (i == 0) rowptr[0] = 0;
}

// packed edge record: {col * 256 (byte offset of fp16 row), bitcast(dinv[col])}
__global__ void fill_kernel(const int* __restrict__ row, const int* __restrict__ col,
                            const int* __restrict__ rowptr, int* __restrict__ cursor,
                            const float* __restrict__ dinv,
                            int2* __restrict__ colwt) {
    int e = blockIdx.x * blockDim.x + threadIdx.x;
    if (e < N_EDGES) {
        int r = row[e], c = col[e];
        int pos = rowptr[r] + atomicAdd(&cursor[r], 1);
        colwt[pos] = make_int2(c * (F * 2), __float_as_int(dinv[c]));
    }
}

// ---------------- x -> fp16 ----------------
__global__ void x2half_kernel(const float* __restrict__ x, __half* __restrict__ xh) {
    int idx = blockIdx.x * 256 + threadIdx.x;   // one per 8 elems; grid 3125
    float4 f0 = ((const float4*)x)[idx * 2];
    float4 f1 = ((const float4*)x)[idx * 2 + 1];
    H8 o;
    o.h2[0] = __float22half2_rn(make_float2(f0.x, f0.y));
    o.h2[1] = __float22half2_rn(make_float2(f0.z, f0.w));
    o.h2[2] = __float22half2_rn(make_float2(f1.x, f1.y));
    o.h2[3] = __float22half2_rn(make_float2(f1.z, f1.w));
    ((uint4*)xh)[idx] = o.u;
}

// ---------------- pack W into B-fragment order ----------------
// B[k][n] = W[n][k]; fragment: lane holds B[k0+(lane>>4)*8+j][n0*16+(lane&15)]
// Bp[layer][t*1024 + lane*8 + j], t = (k0/32)*8 + n0
__global__ void pack_b_kernel(const float* __restrict__ W1, const float* __restrict__ W2,
                              const float* __restrict__ W3, _Float16* __restrict__ Bp) {
    int idx = blockIdx.x * 256 + threadIdx.x;   // 3*2048 = 6144 -> 24 blocks
    int layer = idx >> 11;
    int r = idx & 2047;
    int t = r >> 6, lane = r & 63;
    int s = t >> 3, n0 = t & 7;
    int n = n0 * 16 + (lane & 15);
    int k = s * 32 + (lane >> 4) * 8;
    const float* W = (layer == 0) ? W1 : (layer == 1) ? W2 : W3;
    float4 f0 = *(const float4*)(W + n * 128 + k);
    float4 f1 = *(const float4*)(W + n * 128 + k + 4);
    _Float16* dst = Bp + (size_t)layer * 32768 + (size_t)r * 8;
    dst[0] = (_Float16)f0.x; dst[1] = (_Float16)f0.y;
    dst[2] = (_Float16)f0.z; dst[3] = (_Float16)f0.w;
    dst[4] = (_Float16)f1.x; dst[5] = (_Float16)f1.y;
    dst[6] = (_Float16)f1.z; dst[7] = (_Float16)f1.w;
}

// ---------------- fused high-pass (fp16 rows, quarter-wave per edge) ----------------
// out[i][:] = f(h[i][:]) - ALPHA*dinv[i]*sum_e w_e * f(h[col_e][:])
// wave per row; quarter q handles edges e0+q, e0+q+4, ...; lane-in-quarter l
// owns cols l*8..l*8+7 (16 B). Quarters combined via shfl_xor(16|32).
template <int USEBN>
__global__ __launch_bounds__(256) void hp_kernel(
        const __half* __restrict__ h,
        const float* __restrict__ scale, const float* __restrict__ shift,
        const float* __restrict__ dinv, const int* __restrict__ rowptr,
        const int2* __restrict__ colwt, __half* __restrict__ out) {
    int lane = threadIdx.x & 63;
    int q = lane >> 4;
    int l = lane & 15;
    int i = blockIdx.x * 4 + (threadIdx.x >> 6);   // 4 waves/block, 1 row each

    float sc[8], sh[8];
    if (USEBN) {
        float4 a0 = ((const float4*)scale)[l * 2];
        float4 a1 = ((const float4*)scale)[l * 2 + 1];
        float4 b0 = ((const float4*)shift)[l * 2];
        float4 b1 = ((const float4*)shift)[l * 2 + 1];
        sc[0] = a0.x; sc[1] = a0.y; sc[2] = a0.z; sc[3] = a0.w;
        sc[4] = a1.x; sc[5] = a1.y; sc[6] = a1.z; sc[7] = a1.w;
        sh[0] = b0.x; sh[1] = b0.y; sh[2] = b0.z; sh[3] = b0.w;
        sh[4] = b1.x; sh[5] = b1.y; sh[6] = b1.z; sh[7] = b1.w;
    }

    int e0 = rowptr[i], e1 = rowptr[i + 1];
    const char* hb = (const char*)h;
    int loff = l * 16;
    float acc[8] = {0.f, 0.f, 0.f, 0.f, 0.f, 0.f, 0.f, 0.f};

    int e = e0 + q;
    for (; e + 4 < e1; e += 8) {   // 2 edges per quarter per iter
        int2 cw0 = colwt[e];
        int2 cw1 = colwt[e + 4];
        H8 r0, r1;
        r0.u = *(const uint4*)(hb + (size_t)(cw0.x + loff));
        r1.u = *(const uint4*)(hb + (size_t)(cw1.x + loff));
        float w0 = __int_as_float(cw0.y), w1 = __int_as_float(cw1.y);
        #pragma unroll
        for (int p = 0; p < 4; ++p) {
            float2 f0 = __half22float2(r0.h2[p]);
            float2 f1 = __half22float2(r1.h2[p]);
            if (USEBN) {
                f0.x = fmaxf(fmaf(f0.x, sc[2 * p], sh[2 * p]), 0.f);
                f0.y = fmaxf(fmaf(f0.y, sc[2 * p + 1], sh[2 * p + 1]), 0.f);
                f1.x = fmaxf(fmaf(f1.x, sc[2 * p], sh[2 * p]), 0.f);
                f1.y = fmaxf(fmaf(f1.y, sc[2 * p + 1], sh[2 * p + 1]), 0.f);
            }
            acc[2 * p]     = fmaf(w0, f0.x, acc[2 * p]);
            acc[2 * p + 1] = fmaf(w0, f0.y, acc[2 * p + 1]);
            acc[2 * p]     = fmaf(w1, f1.x, acc[2 * p]);
            acc[2 * p + 1] = fmaf(w1, f1.y, acc[2 * p + 1]);
        }
    }
    for (; e < e1; e += 4) {
        int2 cw = colwt[e];
        H8 r0;
        r0.u = *(const uint4*)(hb + (size_t)(cw.x + loff));
        float w0 = __int_as_float(cw.y);
        #pragma unroll
        for (int p = 0; p < 4; ++p) {
            float2 f0 = __half22float2(r0.h2[p]);
            if (USEBN) {
                f0.x = fmaxf(fmaf(f0.x, sc[2 * p], sh[2 * p]), 0.f);
                f0.y = fmaxf(fmaf(f0.y, sc[2 * p + 1], sh[2 * p + 1]), 0.f);
            }
            acc[2 * p]     = fmaf(w0, f0.x, acc[2 * p]);
            acc[2 * p + 1] = fmaf(w0, f0.y, acc[2 * p + 1]);
        }
    }

    #pragma unroll
    for (int c = 0; c < 8; ++c) {
        acc[c] += __shfl_xor(acc[c], 16);
        acc[c] += __shfl_xor(acc[c], 32);
    }

    float a = ALPHA * dinv[i];
    if (q == 0) {
        H8 s8, o;
        s8.u = *(const uint4*)(hb + (size_t)i * 256 + loff);
        #pragma unroll
        for (int p = 0; p < 4; ++p) {
            float2 f = __half22float2(s8.h2[p]);
            if (USEBN) {
                f.x = fmaxf(fmaf(f.x, sc[2 * p], sh[2 * p]), 0.f);
                f.y = fmaxf(fmaf(f.y, sc[2 * p + 1], sh[2 * p + 1]), 0.f);
            }
            o.h2[p] = __float22half2_rn(
                make_float2(f.x - a * acc[2 * p], f.y - a * acc[2 * p + 1]));
        }
        *(uint4*)((char*)out + (size_t)i * 256 + loff) = o.u;
    }
}

// ---------------- MFMA GEMM: out[M x 128] = A_half @ B + bias ----------------
// MODE 0: half out + fused BN col partials; MODE 1: f32 out, no stats.
// wave w: rows row0 = blk*64 + w*16, all 128 cols via 8 n0-tiles.
// A-frag: lane holds A[row0 + (lane&15)][k = s*32 + (lane>>4)*8 + j]
// C/D: col = lane&15 (+n0*16), row = (lane>>4)*4 + reg  [m89-verified]
template <int MODE>
__global__ __launch_bounds__(256) void gemm_kernel(
        const __half* __restrict__ A, const _Float16* __restrict__ Bp,
        const float* __restrict__ bias, void* __restrict__ outv,
        float* __restrict__ partial, int M) {
    __shared__ float st_s[4][128];
    __shared__ float st_q[4][128];
    int tid = threadIdx.x;
    int w = tid >> 6, lane = tid & 63;
    int l = lane & 15, g = lane >> 4;
    int row0 = blockIdx.x * 64 + w * 16;
    bool active = row0 < M;   // M % 16 == 0, so waves are all-or-nothing

    const char* Ab = (const char*)A;
    half8_t a[4];
    if (active) {
        #pragma unroll
        for (int s = 0; s < 4; ++s)
            a[s] = *(const half8_t*)(Ab + (size_t)(row0 + l) * 256 + s * 64 + g * 16);
    } else {
        half8_t z = 0;
        a[0] = z; a[1] = z; a[2] = z; a[3] = z;
    }

    #pragma unroll
    for (int n0 = 0; n0 < 8; ++n0) {
        floatx4 acc = {0.f, 0.f, 0.f, 0.f};
        #pragma unroll
        for (int s = 0; s < 4; ++s) {
            half8_t b = *(const half8_t*)(Bp + ((size_t)(s * 8 + n0) * 64 + lane) * 8);
            acc = __builtin_amdgcn_mfma_f32_16x16x32_f16(a[s], b, acc, 0, 0, 0);
        }
        int col = n0 * 16 + l;
        float bv = bias[col];
        float v0 = acc[0] + bv, v1 = acc[1] + bv, v2 = acc[2] + bv, v3 = acc[3] + bv;
        if (active) {
            int r = row0 + g * 4;
            if (MODE == 0) {
                __half* oh = (__half*)outv;
                oh[(size_t)r * 128 + col]       = __float2half_rn(v0);
                oh[(size_t)(r + 1) * 128 + col] = __float2half_rn(v1);
                oh[(size_t)(r + 2) * 128 + col] = __float2half_rn(v2);
                oh[(size_t)(r + 3) * 128 + col] = __float2half_rn(v3);
            } else {
                float* of = (float*)outv;
                of[(size_t)r * 128 + col]       = v0;
                of[(size_t)(r + 1) * 128 + col] = v1;
                of[(size_t)(r + 2) * 128 + col] = v2;
                of[(size_t)(r + 3) * 128 + col] = v3;
            }
        } else {
            v0 = v1 = v2 = v3 = 0.f;
        }
        if (MODE == 0) {
            float s_ = v0 + v1 + v2 + v3;
            float q_ = v0 * v0 + v1 * v1 + v2 * v2 + v3 * v3;
            s_ += __shfl_xor(s_, 16); s_ += __shfl_xor(s_, 32);
            q_ += __shfl_xor(q_, 16); q_ += __shfl_xor(q_, 32);
            if (lane < 16) { st_s[w][col] = s_; st_q[w][col] = q_; }
        }
    }
    if (MODE == 0) {
        __syncthreads();
        if (tid < 128) {
            partial[(size_t)blockIdx.x * 256 + tid] =
                st_s[0][tid] + st_s[1][tid] + st_s[2][tid] + st_s[3][tid];
            partial[(size_t)blockIdx.x * 256 + 128 + tid] =
                st_q[0][tid] + st_q[1][tid] + st_q[2][tid] + st_q[3][tid];
        }
    }
}

// ---------------- BN reduce: 128 blocks, one column each ----------------
__global__ __launch_bounds__(256) void bn_reduce_kernel(
        const float* __restrict__ partial,
        const float* __restrict__ g, const float* __restrict__ bt,
        float* __restrict__ scale, float* __restrict__ shift) {
    __shared__ float ss[256], sq[256];
    int j = blockIdx.x;       // 0..127
    int tid = threadIdx.x;    // 0..255
    float s = 0.f, q = 0.f;
    for (int b = tid; b < GEMM_NBLK; b += 256) {
        s += partial[(size_t)b * 256 + j];
        q += partial[(size_t)b * 256 + 128 + j];
    }
    ss[tid] = s; sq[tid] = q;
    __syncthreads();
    for (int off = 128; off > 0; off >>= 1) {
        if (tid < off) { ss[tid] += ss[tid + off]; sq[tid] += sq[tid + off]; }
        __syncthreads();
    }
    if (tid == 0) {
        float m = ss[0] / (float)N_NODES;
        float v = sq[0] / (float)N_NODES - m * m;
        float sc = g[j] * rsqrtf(v + BN_EPS);
        scale[j] = sc;
        shift[j] = bt[j] - m * sc;
    }
}

// ---------------- launch ----------------

extern "C" void kernel_launch(void* const* d_in, const int* in_sizes, int n_in,
                              void* d_out, int out_size, void* d_ws, size_t ws_size,
                              hipStream_t stream) {
    const float* x   = (const float*)d_in[0];
    const int*   ei  = (const int*)d_in[1];
    const float* W1  = (const float*)d_in[2];
    const float* b1  = (const float*)d_in[3];
    const float* W2  = (const float*)d_in[4];
    const float* b2  = (const float*)d_in[5];
    const float* W3  = (const float*)d_in[6];
    const float* b3  = (const float*)d_in[7];
    const float* g1  = (const float*)d_in[8];
    const float* bt1 = (const float*)d_in[9];
    const float* g2  = (const float*)d_in[10];
    const float* bt2 = (const float*)d_in[11];
    float* out = (float*)d_out;

    const int* row = ei;
    const int* col = ei + N_EDGES;

    char* ws = (char*)d_ws;
    size_t off = 0;
    auto alloc = [&](size_t bytes) -> void* {
        void* p = ws + off;
        off += (bytes + 255) & ~(size_t)255;
        return p;
    };
    int*   deg      = (int*)alloc(N_NODES * 4);
    int*   cursor   = (int*)alloc(N_NODES * 4);
    size_t zero_bytes = off;  // only deg+cursor need zeroing
    int*   rowptr   = (int*)alloc((N_NODES + 1) * 4);
    int*   localscan= (int*)alloc(N_NODES * 4);
    int*   blocksum = (int*)alloc(NB_SCAN * 4);
    float* dinv     = (float*)alloc(N_NODES * 4);
    int2*  colwt    = (int2*)alloc((size_t)N_EDGES * 8);
    _Float16* Bp    = (_Float16*)alloc(3 * 32768 * 2);
    float* partial  = (float*)alloc((size_t)GEMM_NBLK * 256 * 4);
    float* scale1   = (float*)alloc(F * 4);
    float* shift1   = (float*)alloc(F * 4);
    float* scale2   = (float*)alloc(F * 4);
    float* shift2   = (float*)alloc(F * 4);
    __half* xh      = (__half*)alloc((size_t)N_NODES * F * 2);
    __half* hpA     = (__half*)alloc((size_t)(N_NODES + 64) * F * 2);  // pad for last gemm block
    __half* hB      = (__half*)alloc((size_t)N_NODES * F * 2);
    (void)ws_size; (void)n_in; (void)in_sizes; (void)out_size;

    hipMemsetAsync(d_ws, 0, zero_bytes, stream);

    x2half_kernel<<<3125, 256, 0, stream>>>(x, xh);
    pack_b_kernel<<<24, 256, 0, stream>>>(W1, W2, W3, Bp);

    deg_kernel<<<(N_EDGES + 255) / 256, 256, 0, stream>>>(row, deg);
    scan_block<<<NB_SCAN, 256, 0, stream>>>(deg, localscan, blocksum, dinv);
    scan_tops<<<1, 256, 0, stream>>>(blocksum);
    scan_add<<<NB_SCAN, 256, 0, stream>>>(localscan, blocksum, rowptr);
    fill_kernel<<<(N_EDGES + 255) / 256, 256, 0, stream>>>(row, col, rowptr, cursor,
                                                           dinv, colwt);

    const int hp_grid = N_NODES / 4;  // 4 waves/block, 1 row per wave

    // layer 0
    hp_kernel<0><<<hp_grid, 256, 0, stream>>>(xh, nullptr, nullptr, dinv, rowptr,
                                              colwt, hpA);
    gemm_kernel<0><<<GEMM_NBLK, 256, 0, stream>>>(hpA, Bp, b1, hB, partial, N_NODES);
    bn_reduce_kernel<<<128, 256, 0, stream>>>(partial, g1, bt1, scale1, shift1);

    // layer 1
    hp_kernel<1><<<hp_grid, 256, 0, stream>>>(hB, scale1, shift1, dinv, rowptr,
                                              colwt, hpA);
    gemm_kernel<0><<<GEMM_NBLK, 256, 0, stream>>>(hpA, Bp + 32768, b2, hB, partial,
                                                  N_NODES);
    bn_reduce_kernel<<<128, 256, 0, stream>>>(partial, g2, bt2, scale2, shift2);

    // layer 2 (output, f32)
    hp_kernel<1><<<hp_grid, 256, 0, stream>>>(hB, scale2, shift2, dinv, rowptr,
                                              colwt, hpA);
    gemm_kernel<1><<<GEMM_NBLK, 256, 0, stream>>>(hpA, Bp + 65536, b3, out, nullptr,
                                                  N_NODES);
}

// Round 7
// 244.858 us; speedup vs baseline: 3.4515x; 1.0232x over previous
//
#include <hip/hip_runtime.h>
#include <hip/hip_fp16.h>

#define N_NODES 50000
#define N_EDGES 800000
#define F 128
#define ALPHA 0.5f
#define BN_EPS 1e-5f
#define NB_SCAN ((N_NODES + 255) / 256)   // 196
#define GEMM_NBLK ((N_NODES + 63) / 64)   // 782

typedef _Float16 half8_t __attribute__((ext_vector_type(8)));
typedef float floatx4 __attribute__((ext_vector_type(4)));

union H8 { uint4 u; __half2 h2[4]; };

// ---------------- fused prep: x->fp16 | pack B fragments | deg histogram ----------------
// blocks [0,3125): x2half ; [3125,3149): pack_b ; [3149,6274): deg atomics
__global__ __launch_bounds__(256) void prep_kernel(
        const float* __restrict__ x, __half* __restrict__ xh,
        const float* __restrict__ W1, const float* __restrict__ W2,
        const float* __restrict__ W3, _Float16* __restrict__ Bp,
        const int* __restrict__ row, int* __restrict__ deg) {
    int bid = blockIdx.x;
    if (bid < 3125) {
        int idx = bid * 256 + threadIdx.x;   // one per 8 elems
        float4 f0 = ((const float4*)x)[idx * 2];
        float4 f1 = ((const float4*)x)[idx * 2 + 1];
        H8 o;
        o.h2[0] = __float22half2_rn(make_float2(f0.x, f0.y));
        o.h2[1] = __float22half2_rn(make_float2(f0.z, f0.w));
        o.h2[2] = __float22half2_rn(make_float2(f1.x, f1.y));
        o.h2[3] = __float22half2_rn(make_float2(f1.z, f1.w));
        ((uint4*)xh)[idx] = o.u;
    } else if (bid < 3149) {
        // B[k][n] = W[n][k]; lane holds B[k0+(lane>>4)*8+j][n0*16+(lane&15)]
        int idx = (bid - 3125) * 256 + threadIdx.x;   // 3*2048 = 6144
        int layer = idx >> 11;
        int r = idx & 2047;
        int t = r >> 6, lane = r & 63;
        int s = t >> 3, n0 = t & 7;
        int n = n0 * 16 + (lane & 15);
        int k = s * 32 + (lane >> 4) * 8;
        const float* W = (layer == 0) ? W1 : (layer == 1) ? W2 : W3;
        float4 f0 = *(const float4*)(W + n * 128 + k);
        float4 f1 = *(const float4*)(W + n * 128 + k + 4);
        _Float16* dst = Bp + (size_t)layer * 32768 + (size_t)r * 8;
        dst[0] = (_Float16)f0.x; dst[1] = (_Float16)f0.y;
        dst[2] = (_Float16)f0.z; dst[3] = (_Float16)f0.w;
        dst[4] = (_Float16)f1.x; dst[5] = (_Float16)f1.y;
        dst[6] = (_Float16)f1.z; dst[7] = (_Float16)f1.w;
    } else {
        int e = (bid - 3149) * 256 + threadIdx.x;
        if (e < N_EDGES) atomicAdd(&deg[row[e]], 1);
    }
}

// ---------------- scan: per-block inclusive scan (+dinv), then add-with-tops ----------------

__global__ void scan_block(const int* __restrict__ deg, int* __restrict__ localscan,
                           int* __restrict__ blocksum, float* __restrict__ dinv) {
    __shared__ int s[256];
    int i = blockIdx.x * 256 + threadIdx.x;
    int v = (i < N_NODES) ? deg[i] : 0;
    if (i < N_NODES) dinv[i] = v > 0 ? rsqrtf((float)v) : 0.f;
    s[threadIdx.x] = v;
    __syncthreads();
    for (int off = 1; off < 256; off <<= 1) {
        int t = (threadIdx.x >= off) ? s[threadIdx.x - off] : 0;
        __syncthreads();
        s[threadIdx.x] += t;
        __syncthreads();
    }
    if (i < N_NODES) localscan[i] = s[threadIdx.x];
    if (threadIdx.x == 255) blocksum[blockIdx.x] = s[255];
}

// every block re-scans the 196 block sums in LDS (exclusive prefix of own bid)
__global__ void scan_add_tops(const int* __restrict__ localscan,
                              const int* __restrict__ blocksum,
                              int* __restrict__ rowptr) {
    __shared__ int s[256];
    int v = (threadIdx.x < NB_SCAN) ? blocksum[threadIdx.x] : 0;
    s[threadIdx.x] = v;
    __syncthreads();
    for (int off = 1; off < 256; off <<= 1) {
        int t = (threadIdx.x >= off) ? s[threadIdx.x - off] : 0;
        __syncthreads();
        s[threadIdx.x] += t;
        __syncthreads();
    }
    // exclusive prefix for this block
    int base = (blockIdx.x > 0) ? s[blockIdx.x - 1] : 0;
    int i = blockIdx.x * 256 + threadIdx.x;
    if (i < N_NODES) rowptr[i + 1] = localscan[i] + base;
    if (i == 0) rowptr[0] = 0;
}

// ---------------- fill: packed 4B edge record {u16 col, f16 dinv[col]} ----------------

__global__ void fill_kernel(const int* __restrict__ row, const int* __restrict__ col,
                            const int* __restrict__ rowptr, int* __restrict__ cursor,
                            const float* __restrict__ dinv,
                            unsigned int* __restrict__ colwt) {
    int e = blockIdx.x * blockDim.x + threadIdx.x;
    if (e < N_EDGES) {
        int r = row[e], c = col[e];
        int pos = rowptr[r] + atomicAdd(&cursor[r], 1);
        unsigned int hb = __half_as_ushort(__float2half(dinv[c]));
        colwt[pos] = (unsigned int)c | (hb << 16);
    }
}

// ---------------- fused high-pass (fp16 rows, quarter-wave per edge) ----------------
// out[i][:] = f(h[i][:]) - ALPHA*dinv[i]*sum_e w_e * f(h[col_e][:])
// wave per row; quarter q handles edges e0+q, e0+q+4, ...; lane-in-quarter l
// owns cols l*8..l*8+7 (16 B). Quarters combined via shfl_xor(16|32).
template <int USEBN>
__global__ __launch_bounds__(256) void hp_kernel(
        const __half* __restrict__ h,
        const float* __restrict__ scale, const float* __restrict__ shift,
        const float* __restrict__ dinv, const int* __restrict__ rowptr,
        const unsigned int* __restrict__ colwt, __half* __restrict__ out) {
    int lane = threadIdx.x & 63;
    int q = lane >> 4;
    int l = lane & 15;
    int i = blockIdx.x * 4 + (threadIdx.x >> 6);   // 4 waves/block, 1 row each

    float sc[8], sh[8];
    if (USEBN) {
        float4 a0 = ((const float4*)scale)[l * 2];
        float4 a1 = ((const float4*)scale)[l * 2 + 1];
        float4 b0 = ((const float4*)shift)[l * 2];
        float4 b1 = ((const float4*)shift)[l * 2 + 1];
        sc[0] = a0.x; sc[1] = a0.y; sc[2] = a0.z; sc[3] = a0.w;
        sc[4] = a1.x; sc[5] = a1.y; sc[6] = a1.z; sc[7] = a1.w;
        sh[0] = b0.x; sh[1] = b0.y; sh[2] = b0.z; sh[3] = b0.w;
        sh[4] = b1.x; sh[5] = b1.y; sh[6] = b1.z; sh[7] = b1.w;
    }

    int e0 = rowptr[i], e1 = rowptr[i + 1];
    const char* hb = (const char*)h;
    int loff = l * 16;
    float acc[8] = {0.f, 0.f, 0.f, 0.f, 0.f, 0.f, 0.f, 0.f};

    int e = e0 + q;
    for (; e + 4 < e1; e += 8) {   // 2 edges per quarter per iter
        unsigned int cw0 = colwt[e];
        unsigned int cw1 = colwt[e + 4];
        H8 r0, r1;
        r0.u = *(const uint4*)(hb + (size_t)(cw0 & 0xffffu) * 256 + loff);
        r1.u = *(const uint4*)(hb + (size_t)(cw1 & 0xffffu) * 256 + loff);
        float w0 = __half2float(__ushort_as_half((unsigned short)(cw0 >> 16)));
        float w1 = __half2float(__ushort_as_half((unsigned short)(cw1 >> 16)));
        #pragma unroll
        for (int p = 0; p < 4; ++p) {
            float2 f0 = __half22float2(r0.h2[p]);
            float2 f1 = __half22float2(r1.h2[p]);
            if (USEBN) {
                f0.x = fmaxf(fmaf(f0.x, sc[2 * p], sh[2 * p]), 0.f);
                f0.y = fmaxf(fmaf(f0.y, sc[2 * p + 1], sh[2 * p + 1]), 0.f);
                f1.x = fmaxf(fmaf(f1.x, sc[2 * p], sh[2 * p]), 0.f);
                f1.y = fmaxf(fmaf(f1.y, sc[2 * p + 1], sh[2 * p + 1]), 0.f);
            }
            acc[2 * p]     = fmaf(w0, f0.x, acc[2 * p]);
            acc[2 * p + 1] = fmaf(w0, f0.y, acc[2 * p + 1]);
            acc[2 * p]     = fmaf(w1, f1.x, acc[2 * p]);
            acc[2 * p + 1] = fmaf(w1, f1.y, acc[2 * p + 1]);
        }
    }
    for (; e < e1; e += 4) {
        unsigned int cw = colwt[e];
        H8 r0;
        r0.u = *(const uint4*)(hb + (size_t)(cw & 0xffffu) * 256 + loff);
        float w0 = __half2float(__ushort_as_half((unsigned short)(cw >> 16)));
        #pragma unroll
        for (int p = 0; p < 4; ++p) {
            float2 f0 = __half22float2(r0.h2[p]);
            if (USEBN) {
                f0.x = fmaxf(fmaf(f0.x, sc[2 * p], sh[2 * p]), 0.f);
                f0.y = fmaxf(fmaf(f0.y, sc[2 * p + 1], sh[2 * p + 1]), 0.f);
            }
            acc[2 * p]     = fmaf(w0, f0.x, acc[2 * p]);
            acc[2 * p + 1] = fmaf(w0, f0.y, acc[2 * p + 1]);
        }
    }

    #pragma unroll
    for (int c = 0; c < 8; ++c) {
        acc[c] += __shfl_xor(acc[c], 16);
        acc[c] += __shfl_xor(acc[c], 32);
    }

    float a = ALPHA * dinv[i];
    if (q == 0) {
        H8 s8, o;
        s8.u = *(const uint4*)(hb + (size_t)i * 256 + loff);
        #pragma unroll
        for (int p = 0; p < 4; ++p) {
            float2 f = __half22float2(s8.h2[p]);
            if (USEBN) {
                f.x = fmaxf(fmaf(f.x, sc[2 * p], sh[2 * p]), 0.f);
                f.y = fmaxf(fmaf(f.y, sc[2 * p + 1], sh[2 * p + 1]), 0.f);
            }
            o.h2[p] = __float22half2_rn(
                make_float2(f.x - a * acc[2 * p], f.y - a * acc[2 * p + 1]));
        }
        *(uint4*)((char*)out + (size_t)i * 256 + loff) = o.u;
    }
}

// ---------------- MFMA GEMM: out[M x 128] = A_half @ B + bias ----------------
// MODE 0: half out + fused BN col partials; MODE 1: f32 out, no stats.
template <int MODE>
__global__ __launch_bounds__(256) void gemm_kernel(
        const __half* __restrict__ A, const _Float16* __restrict__ Bp,
        const float* __restrict__ bias, void* __restrict__ outv,
        float* __restrict__ partial, int M) {
    __shared__ float st_s[4][128];
    __shared__ float st_q[4][128];
    int tid = threadIdx.x;
    int w = tid >> 6, lane = tid & 63;
    int l = lane & 15, g = lane >> 4;
    int row0 = blockIdx.x * 64 + w * 16;
    bool active = row0 < M;   // M % 16 == 0, so waves are all-or-nothing

    const char* Ab = (const char*)A;
    half8_t a[4];
    if (active) {
        #pragma unroll
        for (int s = 0; s < 4; ++s)
            a[s] = *(const half8_t*)(Ab + (size_t)(row0 + l) * 256 + s * 64 + g * 16);
    } else {
        half8_t z = 0;
        a[0] = z; a[1] = z; a[2] = z; a[3] = z;
    }

    #pragma unroll
    for (int n0 = 0; n0 < 8; ++n0) {
        floatx4 acc = {0.f, 0.f, 0.f, 0.f};
        #pragma unroll
        for (int s = 0; s < 4; ++s) {
            half8_t b = *(const half8_t*)(Bp + ((size_t)(s * 8 + n0) * 64 + lane) * 8);
            acc = __builtin_amdgcn_mfma_f32_16x16x32_f16(a[s], b, acc, 0, 0, 0);
        }
        int col = n0 * 16 + l;
        float bv = bias[col];
        float v0 = acc[0] + bv, v1 = acc[1] + bv, v2 = acc[2] + bv, v3 = acc[3] + bv;
        if (active) {
            int r = row0 + g * 4;
            if (MODE == 0) {
                __half* oh = (__half*)outv;
                oh[(size_t)r * 128 + col]       = __float2half_rn(v0);
                oh[(size_t)(r + 1) * 128 + col] = __float2half_rn(v1);
                oh[(size_t)(r + 2) * 128 + col] = __float2half_rn(v2);
                oh[(size_t)(r + 3) * 128 + col] = __float2half_rn(v3);
            } else {
                float* of = (float*)outv;
                of[(size_t)r * 128 + col]       = v0;
                of[(size_t)(r + 1) * 128 + col] = v1;
                of[(size_t)(r + 2) * 128 + col] = v2;
                of[(size_t)(r + 3) * 128 + col] = v3;
            }
        } else {
            v0 = v1 = v2 = v3 = 0.f;
        }
        if (MODE == 0) {
            float s_ = v0 + v1 + v2 + v3;
            float q_ = v0 * v0 + v1 * v1 + v2 * v2 + v3 * v3;
            s_ += __shfl_xor(s_, 16); s_ += __shfl_xor(s_, 32);
            q_ += __shfl_xor(q_, 16); q_ += __shfl_xor(q_, 32);
            if (lane < 16) { st_s[w][col] = s_; st_q[w][col] = q_; }
        }
    }
    if (MODE == 0) {
        __syncthreads();
        if (tid < 128) {
            partial[(size_t)blockIdx.x * 256 + tid] =
                st_s[0][tid] + st_s[1][tid] + st_s[2][tid] + st_s[3][tid];
            partial[(size_t)blockIdx.x * 256 + 128 + tid] =
                st_q[0][tid] + st_q[1][tid] + st_q[2][tid] + st_q[3][tid];
        }
    }
}

// ---------------- BN reduce: 128 blocks, one column each ----------------
__global__ __launch_bounds__(256) void bn_reduce_kernel(
        const float* __restrict__ partial,
        const float* __restrict__ g, const float* __restrict__ bt,
        float* __restrict__ scale, float* __restrict__ shift) {
    __shared__ float ss[256], sq[256];
    int j = blockIdx.x;       // 0..127
    int tid = threadIdx.x;    // 0..255
    float s = 0.f, q = 0.f;
    for (int b = tid; b < GEMM_NBLK; b += 256) {
        s += partial[(size_t)b * 256 + j];
        q += partial[(size_t)b * 256 + 128 + j];
    }
    ss[tid] = s; sq[tid] = q;
    __syncthreads();
    for (int off = 128; off > 0; off >>= 1) {
        if (tid < off) { ss[tid] += ss[tid + off]; sq[tid] += sq[tid + off]; }
        __syncthreads();
    }
    if (tid == 0) {
        float m = ss[0] / (float)N_NODES;
        float v = sq[0] / (float)N_NODES - m * m;
        float sc = g[j] * rsqrtf(v + BN_EPS);
        scale[j] = sc;
        shift[j] = bt[j] - m * sc;
    }
}

// ---------------- launch ----------------

extern "C" void kernel_launch(void* const* d_in, const int* in_sizes, int n_in,
                              void* d_out, int out_size, void* d_ws, size_t ws_size,
                              hipStream_t stream) {
    const float* x   = (const float*)d_in[0];
    const int*   ei  = (const int*)d_in[1];
    const float* W1  = (const float*)d_in[2];
    const float* b1  = (const float*)d_in[3];
    const float* W2  = (const float*)d_in[4];
    const float* b2  = (const float*)d_in[5];
    const float* W3  = (const float*)d_in[6];
    const float* b3  = (const float*)d_in[7];
    const float* g1  = (const float*)d_in[8];
    const float* bt1 = (const float*)d_in[9];
    const float* g2  = (const float*)d_in[10];
    const float* bt2 = (const float*)d_in[11];
    float* out = (float*)d_out;

    const int* row = ei;
    const int* col = ei + N_EDGES;

    char* ws = (char*)d_ws;
    size_t off = 0;
    auto alloc = [&](size_t bytes) -> void* {
        void* p = ws + off;
        off += (bytes + 255) & ~(size_t)255;
        return p;
    };
    int*   deg      = (int*)alloc(N_NODES * 4);
    int*   cursor   = (int*)alloc(N_NODES * 4);
    size_t zero_bytes = off;  // only deg+cursor need zeroing
    int*   rowptr   = (int*)alloc((N_NODES + 1) * 4);
    int*   localscan= (int*)alloc(N_NODES * 4);
    int*   blocksum = (int*)alloc(NB_SCAN * 4);
    float* dinv     = (float*)alloc(N_NODES * 4);
    unsigned int* colwt = (unsigned int*)alloc((size_t)N_EDGES * 4);
    _Float16* Bp    = (_Float16*)alloc(3 * 32768 * 2);
    float* partial  = (float*)alloc((size_t)GEMM_NBLK * 256 * 4);
    float* scale1   = (float*)alloc(F * 4);
    float* shift1   = (float*)alloc(F * 4);
    float* scale2   = (float*)alloc(F * 4);
    float* shift2   = (float*)alloc(F * 4);
    __half* xh      = (__half*)alloc((size_t)N_NODES * F * 2);
    __half* hpA     = (__half*)alloc((size_t)(N_NODES + 64) * F * 2);  // pad for last gemm block
    __half* hB      = (__half*)alloc((size_t)N_NODES * F * 2);
    (void)ws_size; (void)n_in; (void)in_sizes; (void)out_size;

    hipMemsetAsync(d_ws, 0, zero_bytes, stream);

    prep_kernel<<<6274, 256, 0, stream>>>(x, xh, W1, W2, W3, Bp, row, deg);
    scan_block<<<NB_SCAN, 256, 0, stream>>>(deg, localscan, blocksum, dinv);
    scan_add_tops<<<NB_SCAN, 256, 0, stream>>>(localscan, blocksum, rowptr);
    fill_kernel<<<(N_EDGES + 255) / 256, 256, 0, stream>>>(row, col, rowptr, cursor,
                                                           dinv, colwt);

    const int hp_grid = N_NODES / 4;  // 4 waves/block, 1 row per wave

    // layer 0
    hp_kernel<0><<<hp_grid, 256, 0, stream>>>(xh, nullptr, nullptr, dinv, rowptr,
                                              colwt, hpA);
    gemm_kernel<0><<<GEMM_NBLK, 256, 0, stream>>>(hpA, Bp, b1, hB, partial, N_NODES);
    bn_reduce_kernel<<<128, 256, 0, stream>>>(partial, g1, bt1, scale1, shift1);

    // layer 1
    hp_kernel<1><<<hp_grid, 256, 0, stream>>>(hB, scale1, shift1, dinv, rowptr,
                                              colwt, hpA);
    gemm_kernel<0><<<GEMM_NBLK, 256, 0, stream>>>(hpA, Bp + 32768, b2, hB, partial,
                                                  N_NODES);
    bn_reduce_kernel<<<128, 256, 0, stream>>>(partial, g2, bt2, scale2, shift2);

    // layer 2 (output, f32)
    hp_kernel<1><<<hp_grid, 256, 0, stream>>>(hB, scale2, shift2, dinv, rowptr,
                                              colwt, hpA);
    gemm_kernel<1><<<GEMM_NBLK, 256, 0, stream>>>(hpA, Bp + 65536, b3, out, nullptr,
                                                  N_NODES);
}

// Round 8
// 244.333 us; speedup vs baseline: 3.4589x; 1.0021x over previous
//
#include <hip/hip_runtime.h>
#include <hip/hip_fp16.h>

#define N_NODES 50000
#define N_EDGES 800000
#define F 128
#define ALPHA 0.5f
#define BN_EPS 1e-5f
#define NB_SCAN ((N_NODES + 255) / 256)   // 196
#define GEMM_NBLK ((N_NODES + 63) / 64)   // 782
#define NGRP 8
#define GRP_ROWS (N_NODES / NGRP)         // 6250
#define EDGES_PER_BLK 2048                // 256 thr * 8 edges
#define NB_CHUNK ((N_EDGES + EDGES_PER_BLK - 1) / EDGES_PER_BLK)  // 391
#define NB_X2H 3125
#define NB_PB 24

typedef _Float16 half8_t __attribute__((ext_vector_type(8)));
typedef float floatx4 __attribute__((ext_vector_type(4)));

union H8 { uint4 u; __half2 h2[4]; };

// ---------------- fused prep: x->fp16 | pack B | partitioned deg histogram ----------------
// blocks [0,3125): x2half ; [3125,3149): pack_b ; rest: deg (8 row-groups)
__global__ __launch_bounds__(256) void prep_kernel(
        const float* __restrict__ x, __half* __restrict__ xh,
        const float* __restrict__ W1, const float* __restrict__ W2,
        const float* __restrict__ W3, _Float16* __restrict__ Bp,
        const int* __restrict__ row, int* __restrict__ deg) {
    int bid = blockIdx.x;
    if (bid < NB_X2H) {
        int idx = bid * 256 + threadIdx.x;   // one per 8 elems
        float4 f0 = ((const float4*)x)[idx * 2];
        float4 f1 = ((const float4*)x)[idx * 2 + 1];
        H8 o;
        o.h2[0] = __float22half2_rn(make_float2(f0.x, f0.y));
        o.h2[1] = __float22half2_rn(make_float2(f0.z, f0.w));
        o.h2[2] = __float22half2_rn(make_float2(f1.x, f1.y));
        o.h2[3] = __float22half2_rn(make_float2(f1.z, f1.w));
        ((uint4*)xh)[idx] = o.u;
    } else if (bid < NB_X2H + NB_PB) {
        // B[k][n] = W[n][k]; lane holds B[k0+(lane>>4)*8+j][n0*16+(lane&15)]
        int idx = (bid - NB_X2H) * 256 + threadIdx.x;   // 3*2048 = 6144
        int layer = idx >> 11;
        int r = idx & 2047;
        int t = r >> 6, lane = r & 63;
        int s = t >> 3, n0 = t & 7;
        int n = n0 * 16 + (lane & 15);
        int k = s * 32 + (lane >> 4) * 8;
        const float* W = (layer == 0) ? W1 : (layer == 1) ? W2 : W3;
        float4 f0 = *(const float4*)(W + n * 128 + k);
        float4 f1 = *(const float4*)(W + n * 128 + k + 4);
        _Float16* dst = Bp + (size_t)layer * 32768 + (size_t)r * 8;
        dst[0] = (_Float16)f0.x; dst[1] = (_Float16)f0.y;
        dst[2] = (_Float16)f0.z; dst[3] = (_Float16)f0.w;
        dst[4] = (_Float16)f1.x; dst[5] = (_Float16)f1.y;
        dst[6] = (_Float16)f1.z; dst[7] = (_Float16)f1.w;
    } else {
        int t = bid - (NB_X2H + NB_PB);
        int g = t & 7;            // row-group; with blockIdx%8 XCD round-robin,
        int chunk = t >> 3;       // all blocks of a group co-locate on one XCD
        int rlo = g * GRP_ROWS, rhi = rlo + GRP_ROWS;
        int base = chunk * EDGES_PER_BLK + threadIdx.x * 8;
        if (base + 8 <= N_EDGES) {
            int4 r0 = *(const int4*)(row + base);
            int4 r1 = *(const int4*)(row + base + 4);
            int rr[8] = {r0.x, r0.y, r0.z, r0.w, r1.x, r1.y, r1.z, r1.w};
            #pragma unroll
            for (int k = 0; k < 8; ++k)
                if (rr[k] >= rlo && rr[k] < rhi) atomicAdd(&deg[rr[k]], 1);
        } else {
            for (int e = base; e < N_EDGES; ++e) {
                int r = row[e];
                if (r >= rlo && r < rhi) atomicAdd(&deg[r], 1);
            }
        }
    }
}

// ---------------- scan: per-block inclusive scan (+dinv), then add-with-tops ----------------

__global__ void scan_block(const int* __restrict__ deg, int* __restrict__ localscan,
                           int* __restrict__ blocksum, float* __restrict__ dinv) {
    __shared__ int s[256];
    int i = blockIdx.x * 256 + threadIdx.x;
    int v = (i < N_NODES) ? deg[i] : 0;
    if (i < N_NODES) dinv[i] = v > 0 ? rsqrtf((float)v) : 0.f;
    s[threadIdx.x] = v;
    __syncthreads();
    for (int off = 1; off < 256; off <<= 1) {
        int t = (threadIdx.x >= off) ? s[threadIdx.x - off] : 0;
        __syncthreads();
        s[threadIdx.x] += t;
        __syncthreads();
    }
    if (i < N_NODES) localscan[i] = s[threadIdx.x];
    if (threadIdx.x == 255) blocksum[blockIdx.x] = s[255];
}

// every block re-scans the 196 block sums in LDS (exclusive prefix of own bid)
__global__ void scan_add_tops(const int* __restrict__ localscan,
                              const int* __restrict__ blocksum,
                              int* __restrict__ rowptr) {
    __shared__ int s[256];
    int v = (threadIdx.x < NB_SCAN) ? blocksum[threadIdx.x] : 0;
    s[threadIdx.x] = v;
    __syncthreads();
    for (int off = 1; off < 256; off <<= 1) {
        int t = (threadIdx.x >= off) ? s[threadIdx.x - off] : 0;
        __syncthreads();
        s[threadIdx.x] += t;
        __syncthreads();
    }
    int base = (blockIdx.x > 0) ? s[blockIdx.x - 1] : 0;
    int i = blockIdx.x * 256 + threadIdx.x;
    if (i < N_NODES) rowptr[i + 1] = localscan[i] + base;
    if (i == 0) rowptr[0] = 0;
}

// ---------------- fill (partitioned by row-group, 8 edges/thread) ----------------
// packed 4B edge record {u16 col, f16 dinv[col]}

__global__ __launch_bounds__(256) void fill_kernel(
        const int* __restrict__ row, const int* __restrict__ col,
        const int* __restrict__ rowptr, int* __restrict__ cursor,
        const float* __restrict__ dinv, unsigned int* __restrict__ colwt) {
    int t = blockIdx.x;
    int g = t & 7;
    int chunk = t >> 3;
    int rlo = g * GRP_ROWS, rhi = rlo + GRP_ROWS;
    int base = chunk * EDGES_PER_BLK + threadIdx.x * 8;

    if (base + 8 <= N_EDGES) {
        int4 r0 = *(const int4*)(row + base);
        int4 r1 = *(const int4*)(row + base + 4);
        int4 c0 = *(const int4*)(col + base);
        int4 c1 = *(const int4*)(col + base + 4);
        int rr[8] = {r0.x, r0.y, r0.z, r0.w, r1.x, r1.y, r1.z, r1.w};
        int cc[8] = {c0.x, c0.y, c0.z, c0.w, c1.x, c1.y, c1.z, c1.w};
        #pragma unroll
        for (int k = 0; k < 8; ++k) {
            if (rr[k] >= rlo && rr[k] < rhi) {
                int pos = rowptr[rr[k]] + atomicAdd(&cursor[rr[k]], 1);
                unsigned int hb = __half_as_ushort(__float2half(dinv[cc[k]]));
                colwt[pos] = (unsigned int)cc[k] | (hb << 16);
            }
        }
    } else {
        for (int e = base; e < N_EDGES; ++e) {
            int r = row[e];
            if (r >= rlo && r < rhi) {
                int c = col[e];
                int pos = rowptr[r] + atomicAdd(&cursor[r], 1);
                unsigned int hb = __half_as_ushort(__float2half(dinv[c]));
                colwt[pos] = (unsigned int)c | (hb << 16);
            }
        }
    }
}

// ---------------- fused high-pass (fp16 rows, quarter-wave per edge) ----------------
template <int USEBN>
__global__ __launch_bounds__(256) void hp_kernel(
        const __half* __restrict__ h,
        const float* __restrict__ scale, const float* __restrict__ shift,
        const float* __restrict__ dinv, const int* __restrict__ rowptr,
        const unsigned int* __restrict__ colwt, __half* __restrict__ out) {
    int lane = threadIdx.x & 63;
    int q = lane >> 4;
    int l = lane & 15;
    int i = blockIdx.x * 4 + (threadIdx.x >> 6);   // 4 waves/block, 1 row each

    float sc[8], sh[8];
    if (USEBN) {
        float4 a0 = ((const float4*)scale)[l * 2];
        float4 a1 = ((const float4*)scale)[l * 2 + 1];
        float4 b0 = ((const float4*)shift)[l * 2];
        float4 b1 = ((const float4*)shift)[l * 2 + 1];
        sc[0] = a0.x; sc[1] = a0.y; sc[2] = a0.z; sc[3] = a0.w;
        sc[4] = a1.x; sc[5] = a1.y; sc[6] = a1.z; sc[7] = a1.w;
        sh[0] = b0.x; sh[1] = b0.y; sh[2] = b0.z; sh[3] = b0.w;
        sh[4] = b1.x; sh[5] = b1.y; sh[6] = b1.z; sh[7] = b1.w;
    }

    int e0 = rowptr[i], e1 = rowptr[i + 1];
    const char* hb = (const char*)h;
    int loff = l * 16;
    float acc[8] = {0.f, 0.f, 0.f, 0.f, 0.f, 0.f, 0.f, 0.f};

    int e = e0 + q;
    for (; e + 4 < e1; e += 8) {   // 2 edges per quarter per iter
        unsigned int cw0 = colwt[e];
        unsigned int cw1 = colwt[e + 4];
        H8 r0, r1;
        r0.u = *(const uint4*)(hb + (size_t)(cw0 & 0xffffu) * 256 + loff);
        r1.u = *(const uint4*)(hb + (size_t)(cw1 & 0xffffu) * 256 + loff);
        float w0 = __half2float(__ushort_as_half((unsigned short)(cw0 >> 16)));
        float w1 = __half2float(__ushort_as_half((unsigned short)(cw1 >> 16)));
        #pragma unroll
        for (int p = 0; p < 4; ++p) {
            float2 f0 = __half22float2(r0.h2[p]);
            float2 f1 = __half22float2(r1.h2[p]);
            if (USEBN) {
                f0.x = fmaxf(fmaf(f0.x, sc[2 * p], sh[2 * p]), 0.f);
                f0.y = fmaxf(fmaf(f0.y, sc[2 * p + 1], sh[2 * p + 1]), 0.f);
                f1.x = fmaxf(fmaf(f1.x, sc[2 * p], sh[2 * p]), 0.f);
                f1.y = fmaxf(fmaf(f1.y, sc[2 * p + 1], sh[2 * p + 1]), 0.f);
            }
            acc[2 * p]     = fmaf(w0, f0.x, acc[2 * p]);
            acc[2 * p + 1] = fmaf(w0, f0.y, acc[2 * p + 1]);
            acc[2 * p]     = fmaf(w1, f1.x, acc[2 * p]);
            acc[2 * p + 1] = fmaf(w1, f1.y, acc[2 * p + 1]);
        }
    }
    for (; e < e1; e += 4) {
        unsigned int cw = colwt[e];
        H8 r0;
        r0.u = *(const uint4*)(hb + (size_t)(cw & 0xffffu) * 256 + loff);
        float w0 = __half2float(__ushort_as_half((unsigned short)(cw >> 16)));
        #pragma unroll
        for (int p = 0; p < 4; ++p) {
            float2 f0 = __half22float2(r0.h2[p]);
            if (USEBN) {
                f0.x = fmaxf(fmaf(f0.x, sc[2 * p], sh[2 * p]), 0.f);
                f0.y = fmaxf(fmaf(f0.y, sc[2 * p + 1], sh[2 * p + 1]), 0.f);
            }
            acc[2 * p]     = fmaf(w0, f0.x, acc[2 * p]);
            acc[2 * p + 1] = fmaf(w0, f0.y, acc[2 * p + 1]);
        }
    }

    #pragma unroll
    for (int c = 0; c < 8; ++c) {
        acc[c] += __shfl_xor(acc[c], 16);
        acc[c] += __shfl_xor(acc[c], 32);
    }

    float a = ALPHA * dinv[i];
    if (q == 0) {
        H8 s8, o;
        s8.u = *(const uint4*)(hb + (size_t)i * 256 + loff);
        #pragma unroll
        for (int p = 0; p < 4; ++p) {
            float2 f = __half22float2(s8.h2[p]);
            if (USEBN) {
                f.x = fmaxf(fmaf(f.x, sc[2 * p], sh[2 * p]), 0.f);
                f.y = fmaxf(fmaf(f.y, sc[2 * p + 1], sh[2 * p + 1]), 0.f);
            }
            o.h2[p] = __float22half2_rn(
                make_float2(f.x - a * acc[2 * p], f.y - a * acc[2 * p + 1]));
        }
        *(uint4*)((char*)out + (size_t)i * 256 + loff) = o.u;
    }
}

// ---------------- MFMA GEMM: out[M x 128] = A_half @ B + bias ----------------
// MODE 0: half out + fused BN col partials; MODE 1: f32 out, no stats.
template <int MODE>
__global__ __launch_bounds__(256) void gemm_kernel(
        const __half* __restrict__ A, const _Float16* __restrict__ Bp,
        const float* __restrict__ bias, void* __restrict__ outv,
        float* __restrict__ partial, int M) {
    __shared__ float st_s[4][128];
    __shared__ float st_q[4][128];
    int tid = threadIdx.x;
    int w = tid >> 6, lane = tid & 63;
    int l = lane & 15, g = lane >> 4;
    int row0 = blockIdx.x * 64 + w * 16;
    bool active = row0 < M;   // M % 16 == 0, so waves are all-or-nothing

    const char* Ab = (const char*)A;
    half8_t a[4];
    if (active) {
        #pragma unroll
        for (int s = 0; s < 4; ++s)
            a[s] = *(const half8_t*)(Ab + (size_t)(row0 + l) * 256 + s * 64 + g * 16);
    } else {
        half8_t z = 0;
        a[0] = z; a[1] = z; a[2] = z; a[3] = z;
    }

    #pragma unroll
    for (int n0 = 0; n0 < 8; ++n0) {
        floatx4 acc = {0.f, 0.f, 0.f, 0.f};
        #pragma unroll
        for (int s = 0; s < 4; ++s) {
            half8_t b = *(const half8_t*)(Bp + ((size_t)(s * 8 + n0) * 64 + lane) * 8);
            acc = __builtin_amdgcn_mfma_f32_16x16x32_f16(a[s], b, acc, 0, 0, 0);
        }
        int col = n0 * 16 + l;
        float bv = bias[col];
        float v0 = acc[0] + bv, v1 = acc[1] + bv, v2 = acc[2] + bv, v3 = acc[3] + bv;
        if (active) {
            int r = row0 + g * 4;
            if (MODE == 0) {
                __half* oh = (__half*)outv;
                oh[(size_t)r * 128 + col]       = __float2half_rn(v0);
                oh[(size_t)(r + 1) * 128 + col] = __float2half_rn(v1);
                oh[(size_t)(r + 2) * 128 + col] = __float2half_rn(v2);
                oh[(size_t)(r + 3) * 128 + col] = __float2half_rn(v3);
            } else {
                float* of = (float*)outv;
                of[(size_t)r * 128 + col]       = v0;
                of[(size_t)(r + 1) * 128 + col] = v1;
                of[(size_t)(r + 2) * 128 + col] = v2;
                of[(size_t)(r + 3) * 128 + col] = v3;
            }
        } else {
            v0 = v1 = v2 = v3 = 0.f;
        }
        if (MODE == 0) {
            float s_ = v0 + v1 + v2 + v3;
            float q_ = v0 * v0 + v1 * v1 + v2 * v2 + v3 * v3;
            s_ += __shfl_xor(s_, 16); s_ += __shfl_xor(s_, 32);
            q_ += __shfl_xor(q_, 16); q_ += __shfl_xor(q_, 32);
            if (lane < 16) { st_s[w][col] = s_; st_q[w][col] = q_; }
        }
    }
    if (MODE == 0) {
        __syncthreads();
        if (tid < 128) {
            partial[(size_t)blockIdx.x * 256 + tid] =
                st_s[0][tid] + st_s[1][tid] + st_s[2][tid] + st_s[3][tid];
            partial[(size_t)blockIdx.x * 256 + 128 + tid] =
                st_q[0][tid] + st_q[1][tid] + st_q[2][tid] + st_q[3][tid];
        }
    }
}

// ---------------- BN reduce: 128 blocks, one column each ----------------
__global__ __launch_bounds__(256) void bn_reduce_kernel(
        const float* __restrict__ partial,
        const float* __restrict__ g, const float* __restrict__ bt,
        float* __restrict__ scale, float* __restrict__ shift) {
    __shared__ float ss[256], sq[256];
    int j = blockIdx.x;       // 0..127
    int tid = threadIdx.x;    // 0..255
    float s = 0.f, q = 0.f;
    for (int b = tid; b < GEMM_NBLK; b += 256) {
        s += partial[(size_t)b * 256 + j];
        q += partial[(size_t)b * 256 + 128 + j];
    }
    ss[tid] = s; sq[tid] = q;
    __syncthreads();
    for (int off = 128; off > 0; off >>= 1) {
        if (tid < off) { ss[tid] += ss[tid + off]; sq[tid] += sq[tid + off]; }
        __syncthreads();
    }
    if (tid == 0) {
        float m = ss[0] / (float)N_NODES;
        float v = sq[0] / (float)N_NODES - m * m;
        float sc = g[j] * rsqrtf(v + BN_EPS);
        scale[j] = sc;
        shift[j] = bt[j] - m * sc;
    }
}

// ---------------- launch ----------------

extern "C" void kernel_launch(void* const* d_in, const int* in_sizes, int n_in,
                              void* d_out, int out_size, void* d_ws, size_t ws_size,
                              hipStream_t stream) {
    const float* x   = (const float*)d_in[0];
    const int*   ei  = (const int*)d_in[1];
    const float* W1  = (const float*)d_in[2];
    const float* b1  = (const float*)d_in[3];
    const float* W2  = (const float*)d_in[4];
    const float* b2  = (const float*)d_in[5];
    const float* W3  = (const float*)d_in[6];
    const float* b3  = (const float*)d_in[7];
    const float* g1  = (const float*)d_in[8];
    const float* bt1 = (const float*)d_in[9];
    const float* g2  = (const float*)d_in[10];
    const float* bt2 = (const float*)d_in[11];
    float* out = (float*)d_out;

    const int* row = ei;
    const int* col = ei + N_EDGES;

    char* ws = (char*)d_ws;
    size_t off = 0;
    auto alloc = [&](size_t bytes) -> void* {
        void* p = ws + off;
        off += (bytes + 255) & ~(size_t)255;
        return p;
    };
    int*   deg      = (int*)alloc(N_NODES * 4);
    int*   cursor   = (int*)alloc(N_NODES * 4);
    size_t zero_bytes = off;  // only deg+cursor need zeroing
    int*   rowptr   = (int*)alloc((N_NODES + 1) * 4);
    int*   localscan= (int*)alloc(N_NODES * 4);
    int*   blocksum = (int*)alloc(NB_SCAN * 4);
    float* dinv     = (float*)alloc(N_NODES * 4);
    unsigned int* colwt = (unsigned int*)alloc((size_t)N_EDGES * 4);
    _Float16* Bp    = (_Float16*)alloc(3 * 32768 * 2);
    float* partial  = (float*)alloc((size_t)GEMM_NBLK * 256 * 4);
    float* scale1   = (float*)alloc(F * 4);
    float* shift1   = (float*)alloc(F * 4);
    float* scale2   = (float*)alloc(F * 4);
    float* shift2   = (float*)alloc(F * 4);
    __half* xh      = (__half*)alloc((size_t)N_NODES * F * 2);
    __half* hpA     = (__half*)alloc((size_t)(N_NODES + 64) * F * 2);  // pad for last gemm block
    __half* hB      = (__half*)alloc((size_t)N_NODES * F * 2);
    (void)ws_size; (void)n_in; (void)in_sizes; (void)out_size;

    hipMemsetAsync(d_ws, 0, zero_bytes, stream);

    prep_kernel<<<NB_X2H + NB_PB + NGRP * NB_CHUNK, 256, 0, stream>>>(
        x, xh, W1, W2, W3, Bp, row, deg);
    scan_block<<<NB_SCAN, 256, 0, stream>>>(deg, localscan, blocksum, dinv);
    scan_add_tops<<<NB_SCAN, 256, 0, stream>>>(localscan, blocksum, rowptr);
    fill_kernel<<<NGRP * NB_CHUNK, 256, 0, stream>>>(row, col, rowptr, cursor,
                                                     dinv, colwt);

    const int hp_grid = N_NODES / 4;  // 4 waves/block, 1 row per wave

    // layer 0
    hp_kernel<0><<<hp_grid, 256, 0, stream>>>(xh, nullptr, nullptr, dinv, rowptr,
                                              colwt, hpA);
    gemm_kernel<0><<<GEMM_NBLK, 256, 0, stream>>>(hpA, Bp, b1, hB, partial, N_NODES);
    bn_reduce_kernel<<<128, 256, 0, stream>>>(partial, g1, bt1, scale1, shift1);

    // layer 1
    hp_kernel<1><<<hp_grid, 256, 0, stream>>>(hB, scale1, shift1, dinv, rowptr,
                                              colwt, hpA);
    gemm_kernel<0><<<GEMM_NBLK, 256, 0, stream>>>(hpA, Bp + 32768, b2, hB, partial,
                                                  N_NODES);
    bn_reduce_kernel<<<128, 256, 0, stream>>>(partial, g2, bt2, scale2, shift2);

    // layer 2 (output, f32)
    hp_kernel<1><<<hp_grid, 256, 0, stream>>>(hB, scale2, shift2, dinv, rowptr,
                                              colwt, hpA);
    gemm_kernel<1><<<GEMM_NBLK, 256, 0, stream>>>(hpA, Bp + 65536, b3, out, nullptr,
                                                  N_NODES);
}

// Round 9
// 216.780 us; speedup vs baseline: 3.8985x; 1.1271x over previous
//
#include <hip/hip_runtime.h>
#include <hip/hip_fp16.h>

#define N_NODES 50000
#define N_EDGES 800000
#define F 128
#define ALPHA 0.5f
#define BN_EPS 1e-5f
#define NB_SCAN ((N_NODES + 255) / 256)   // 196
#define GEMM_NBLK ((N_NODES + 63) / 64)   // 782
#define NGRP 8
#define GRP_ROWS (N_NODES / NGRP)         // 6250
#define NCHUNK 32
#define CHUNK_I4 (N_EDGES / NCHUNK / 4)   // 6250 int4 per chunk (25000 edges)
#define NB_X2H 3125
#define NB_PB 24
#define NB_HIST (NGRP * NCHUNK)           // 256

typedef _Float16 half8_t __attribute__((ext_vector_type(8)));
typedef float floatx4 __attribute__((ext_vector_type(4)));

union H8 { uint4 u; __half2 h2[4]; };

// ---------------- fused prep: x->fp16 | pack B | LDS-hist counting ----------------
// blocks [0,3125): x2half ; [3125,3149): pack_b ; [3149,3405): subhist
__global__ __launch_bounds__(256) void prep_kernel(
        const float* __restrict__ x, __half* __restrict__ xh,
        const float* __restrict__ W1, const float* __restrict__ W2,
        const float* __restrict__ W3, _Float16* __restrict__ Bp,
        const int* __restrict__ row, int* __restrict__ subhist) {
    int bid = blockIdx.x;
    if (bid < NB_X2H) {
        int idx = bid * 256 + threadIdx.x;   // one per 8 elems
        float4 f0 = ((const float4*)x)[idx * 2];
        float4 f1 = ((const float4*)x)[idx * 2 + 1];
        H8 o;
        o.h2[0] = __float22half2_rn(make_float2(f0.x, f0.y));
        o.h2[1] = __float22half2_rn(make_float2(f0.z, f0.w));
        o.h2[2] = __float22half2_rn(make_float2(f1.x, f1.y));
        o.h2[3] = __float22half2_rn(make_float2(f1.z, f1.w));
        ((uint4*)xh)[idx] = o.u;
    } else if (bid < NB_X2H + NB_PB) {
        // B[k][n] = W[n][k]; lane holds B[k0+(lane>>4)*8+j][n0*16+(lane&15)]
        int idx = (bid - NB_X2H) * 256 + threadIdx.x;   // 3*2048 = 6144
        int layer = idx >> 11;
        int r = idx & 2047;
        int t = r >> 6, lane = r & 63;
        int s = t >> 3, n0 = t & 7;
        int n = n0 * 16 + (lane & 15);
        int k = s * 32 + (lane >> 4) * 8;
        const float* W = (layer == 0) ? W1 : (layer == 1) ? W2 : W3;
        float4 f0 = *(const float4*)(W + n * 128 + k);
        float4 f1 = *(const float4*)(W + n * 128 + k + 4);
        _Float16* dst = Bp + (size_t)layer * 32768 + (size_t)r * 8;
        dst[0] = (_Float16)f0.x; dst[1] = (_Float16)f0.y;
        dst[2] = (_Float16)f0.z; dst[3] = (_Float16)f0.w;
        dst[4] = (_Float16)f1.x; dst[5] = (_Float16)f1.y;
        dst[6] = (_Float16)f1.z; dst[7] = (_Float16)f1.w;
    } else {
        // subhist[c][i] = #edges in chunk c with row i (row-group g only)
        int t = bid - (NB_X2H + NB_PB);
        int g = t & 7, c = t >> 3;
        int rlo = g * GRP_ROWS;
        __shared__ int hist[GRP_ROWS];
        for (int j = threadIdx.x; j < GRP_ROWS; j += 256) hist[j] = 0;
        __syncthreads();
        const int4* r4 = (const int4*)row;
        for (int v = c * CHUNK_I4 + threadIdx.x; v < (c + 1) * CHUNK_I4; v += 256) {
            int4 rr = r4[v];
            if ((unsigned)(rr.x - rlo) < GRP_ROWS) atomicAdd(&hist[rr.x - rlo], 1);
            if ((unsigned)(rr.y - rlo) < GRP_ROWS) atomicAdd(&hist[rr.y - rlo], 1);
            if ((unsigned)(rr.z - rlo) < GRP_ROWS) atomicAdd(&hist[rr.z - rlo], 1);
            if ((unsigned)(rr.w - rlo) < GRP_ROWS) atomicAdd(&hist[rr.w - rlo], 1);
        }
        __syncthreads();
        for (int j = threadIdx.x; j < GRP_ROWS; j += 256)
            subhist[c * N_NODES + rlo + j] = hist[j];
    }
}

// ---------------- scan: chunk-offsets (in place) + deg/dinv + block scan ----------------

__global__ void scan_block(int* __restrict__ subhist, int* __restrict__ localscan,
                           int* __restrict__ blocksum, float* __restrict__ dinv) {
    __shared__ int s[256];
    int i = blockIdx.x * 256 + threadIdx.x;
    int deg = 0;
    if (i < N_NODES) {
        #pragma unroll
        for (int c = 0; c < NCHUNK; ++c) {
            int t = subhist[c * N_NODES + i];
            subhist[c * N_NODES + i] = deg;   // exclusive prefix over chunks
            deg += t;
        }
        dinv[i] = deg > 0 ? rsqrtf((float)deg) : 0.f;
    }
    s[threadIdx.x] = deg;
    __syncthreads();
    for (int off = 1; off < 256; off <<= 1) {
        int t = (threadIdx.x >= off) ? s[threadIdx.x - off] : 0;
        __syncthreads();
        s[threadIdx.x] += t;
        __syncthreads();
    }
    if (i < N_NODES) localscan[i] = s[threadIdx.x];
    if (threadIdx.x == 255) blocksum[blockIdx.x] = s[255];
}

// every block re-scans the 196 block sums in LDS (exclusive prefix of own bid)
__global__ void scan_add_tops(const int* __restrict__ localscan,
                              const int* __restrict__ blocksum,
                              int* __restrict__ rowptr) {
    __shared__ int s[256];
    int v = (threadIdx.x < NB_SCAN) ? blocksum[threadIdx.x] : 0;
    s[threadIdx.x] = v;
    __syncthreads();
    for (int off = 1; off < 256; off <<= 1) {
        int t = (threadIdx.x >= off) ? s[threadIdx.x - off] : 0;
        __syncthreads();
        s[threadIdx.x] += t;
        __syncthreads();
    }
    int base = (blockIdx.x > 0) ? s[blockIdx.x - 1] : 0;
    int i = blockIdx.x * 256 + threadIdx.x;
    if (i < N_NODES) rowptr[i + 1] = localscan[i] + base;
    if (i == 0) rowptr[0] = 0;
}

// ---------------- fill: LDS-cursor counting-sort scatter (no global atomics) ----------------
// packed 4B edge record {u16 col, f16 dinv[col]}

__global__ __launch_bounds__(256) void fill_kernel(
        const int* __restrict__ row, const int* __restrict__ col,
        const int* __restrict__ rowptr, const int* __restrict__ chunkoff,
        const float* __restrict__ dinv, unsigned int* __restrict__ colwt) {
    int t = blockIdx.x;           // 256 blocks: g = t&7, c = t>>3
    int g = t & 7, c = t >> 3;
    int rlo = g * GRP_ROWS;
    __shared__ int cur[GRP_ROWS];
    for (int j = threadIdx.x; j < GRP_ROWS; j += 256)
        cur[j] = rowptr[rlo + j] + chunkoff[c * N_NODES + rlo + j];
    __syncthreads();
    const int4* r4 = (const int4*)row;
    const int4* c4 = (const int4*)col;
    for (int v = c * CHUNK_I4 + threadIdx.x; v < (c + 1) * CHUNK_I4; v += 256) {
        int4 rr = r4[v];
        int4 cc = c4[v];
        int rs[4] = {rr.x, rr.y, rr.z, rr.w};
        int cs[4] = {cc.x, cc.y, cc.z, cc.w};
        #pragma unroll
        for (int k = 0; k < 4; ++k) {
            if ((unsigned)(rs[k] - rlo) < GRP_ROWS) {
                int pos = atomicAdd(&cur[rs[k] - rlo], 1);
                unsigned int hb = __half_as_ushort(__float2half(dinv[cs[k]]));
                colwt[pos] = (unsigned int)cs[k] | (hb << 16);
            }
        }
    }
}

// ---------------- fused high-pass (fp16 rows, quarter-wave per edge) ----------------
template <int USEBN>
__global__ __launch_bounds__(256) void hp_kernel(
        const __half* __restrict__ h,
        const float* __restrict__ scale, const float* __restrict__ shift,
        const float* __restrict__ dinv, const int* __restrict__ rowptr,
        const unsigned int* __restrict__ colwt, __half* __restrict__ out) {
    int lane = threadIdx.x & 63;
    int q = lane >> 4;
    int l = lane & 15;
    int i = blockIdx.x * 4 + (threadIdx.x >> 6);   // 4 waves/block, 1 row each

    float sc[8], sh[8];
    if (USEBN) {
        float4 a0 = ((const float4*)scale)[l * 2];
        float4 a1 = ((const float4*)scale)[l * 2 + 1];
        float4 b0 = ((const float4*)shift)[l * 2];
        float4 b1 = ((const float4*)shift)[l * 2 + 1];
        sc[0] = a0.x; sc[1] = a0.y; sc[2] = a0.z; sc[3] = a0.w;
        sc[4] = a1.x; sc[5] = a1.y; sc[6] = a1.z; sc[7] = a1.w;
        sh[0] = b0.x; sh[1] = b0.y; sh[2] = b0.z; sh[3] = b0.w;
        sh[4] = b1.x; sh[5] = b1.y; sh[6] = b1.z; sh[7] = b1.w;
    }

    int e0 = rowptr[i], e1 = rowptr[i + 1];
    const char* hb = (const char*)h;
    int loff = l * 16;
    float acc[8] = {0.f, 0.f, 0.f, 0.f, 0.f, 0.f, 0.f, 0.f};

    int e = e0 + q;
    for (; e + 4 < e1; e += 8) {   // 2 edges per quarter per iter
        unsigned int cw0 = colwt[e];
        unsigned int cw1 = colwt[e + 4];
        H8 r0, r1;
        r0.u = *(const uint4*)(hb + (size_t)(cw0 & 0xffffu) * 256 + loff);
        r1.u = *(const uint4*)(hb + (size_t)(cw1 & 0xffffu) * 256 + loff);
        float w0 = __half2float(__ushort_as_half((unsigned short)(cw0 >> 16)));
        float w1 = __half2float(__ushort_as_half((unsigned short)(cw1 >> 16)));
        #pragma unroll
        for (int p = 0; p < 4; ++p) {
            float2 f0 = __half22float2(r0.h2[p]);
            float2 f1 = __half22float2(r1.h2[p]);
            if (USEBN) {
                f0.x = fmaxf(fmaf(f0.x, sc[2 * p], sh[2 * p]), 0.f);
                f0.y = fmaxf(fmaf(f0.y, sc[2 * p + 1], sh[2 * p + 1]), 0.f);
                f1.x = fmaxf(fmaf(f1.x, sc[2 * p], sh[2 * p]), 0.f);
                f1.y = fmaxf(fmaf(f1.y, sc[2 * p + 1], sh[2 * p + 1]), 0.f);
            }
            acc[2 * p]     = fmaf(w0, f0.x, acc[2 * p]);
            acc[2 * p + 1] = fmaf(w0, f0.y, acc[2 * p + 1]);
            acc[2 * p]     = fmaf(w1, f1.x, acc[2 * p]);
            acc[2 * p + 1] = fmaf(w1, f1.y, acc[2 * p + 1]);
        }
    }
    for (; e < e1; e += 4) {
        unsigned int cw = colwt[e];
        H8 r0;
        r0.u = *(const uint4*)(hb + (size_t)(cw & 0xffffu) * 256 + loff);
        float w0 = __half2float(__ushort_as_half((unsigned short)(cw >> 16)));
        #pragma unroll
        for (int p = 0; p < 4; ++p) {
            float2 f0 = __half22float2(r0.h2[p]);
            if (USEBN) {
                f0.x = fmaxf(fmaf(f0.x, sc[2 * p], sh[2 * p]), 0.f);
                f0.y = fmaxf(fmaf(f0.y, sc[2 * p + 1], sh[2 * p + 1]), 0.f);
            }
            acc[2 * p]     = fmaf(w0, f0.x, acc[2 * p]);
            acc[2 * p + 1] = fmaf(w0, f0.y, acc[2 * p + 1]);
        }
    }

    #pragma unroll
    for (int c = 0; c < 8; ++c) {
        acc[c] += __shfl_xor(acc[c], 16);
        acc[c] += __shfl_xor(acc[c], 32);
    }

    float a = ALPHA * dinv[i];
    if (q == 0) {
        H8 s8, o;
        s8.u = *(const uint4*)(hb + (size_t)i * 256 + loff);
        #pragma unroll
        for (int p = 0; p < 4; ++p) {
            float2 f = __half22float2(s8.h2[p]);
            if (USEBN) {
                f.x = fmaxf(fmaf(f.x, sc[2 * p], sh[2 * p]), 0.f);
                f.y = fmaxf(fmaf(f.y, sc[2 * p + 1], sh[2 * p + 1]), 0.f);
            }
            o.h2[p] = __float22half2_rn(
                make_float2(f.x - a * acc[2 * p], f.y - a * acc[2 * p + 1]));
        }
        *(uint4*)((char*)out + (size_t)i * 256 + loff) = o.u;
    }
}

// ---------------- MFMA GEMM: out[M x 128] = A_half @ B + bias ----------------
// MODE 0: half out + fused BN col partials; MODE 1: f32 out, no stats.
template <int MODE>
__global__ __launch_bounds__(256) void gemm_kernel(
        const __half* __restrict__ A, const _Float16* __restrict__ Bp,
        const float* __restrict__ bias, void* __restrict__ outv,
        float* __restrict__ partial, int M) {
    __shared__ float st_s[4][128];
    __shared__ float st_q[4][128];
    int tid = threadIdx.x;
    int w = tid >> 6, lane = tid & 63;
    int l = lane & 15, g = lane >> 4;
    int row0 = blockIdx.x * 64 + w * 16;
    bool active = row0 < M;   // M % 16 == 0, so waves are all-or-nothing

    const char* Ab = (const char*)A;
    half8_t a[4];
    if (active) {
        #pragma unroll
        for (int s = 0; s < 4; ++s)
            a[s] = *(const half8_t*)(Ab + (size_t)(row0 + l) * 256 + s * 64 + g * 16);
    } else {
        half8_t z = 0;
        a[0] = z; a[1] = z; a[2] = z; a[3] = z;
    }

    #pragma unroll
    for (int n0 = 0; n0 < 8; ++n0) {
        floatx4 acc = {0.f, 0.f, 0.f, 0.f};
        #pragma unroll
        for (int s = 0; s < 4; ++s) {
            half8_t b = *(const half8_t*)(Bp + ((size_t)(s * 8 + n0) * 64 + lane) * 8);
            acc = __builtin_amdgcn_mfma_f32_16x16x32_f16(a[s], b, acc, 0, 0, 0);
        }
        int col = n0 * 16 + l;
        float bv = bias[col];
        float v0 = acc[0] + bv, v1 = acc[1] + bv, v2 = acc[2] + bv, v3 = acc[3] + bv;
        if (active) {
            int r = row0 + g * 4;
            if (MODE == 0) {
                __half* oh = (__half*)outv;
                oh[(size_t)r * 128 + col]       = __float2half_rn(v0);
                oh[(size_t)(r + 1) * 128 + col] = __float2half_rn(v1);
                oh[(size_t)(r + 2) * 128 + col] = __float2half_rn(v2);
                oh[(size_t)(r + 3) * 128 + col] = __float2half_rn(v3);
            } else {
                float* of = (float*)outv;
                of[(size_t)r * 128 + col]       = v0;
                of[(size_t)(r + 1) * 128 + col] = v1;
                of[(size_t)(r + 2) * 128 + col] = v2;
                of[(size_t)(r + 3) * 128 + col] = v3;
            }
        } else {
            v0 = v1 = v2 = v3 = 0.f;
        }
        if (MODE == 0) {
            float s_ = v0 + v1 + v2 + v3;
            float q_ = v0 * v0 + v1 * v1 + v2 * v2 + v3 * v3;
            s_ += __shfl_xor(s_, 16); s_ += __shfl_xor(s_, 32);
            q_ += __shfl_xor(q_, 16); q_ += __shfl_xor(q_, 32);
            if (lane < 16) { st_s[w][col] = s_; st_q[w][col] = q_; }
        }
    }
    if (MODE == 0) {
        __syncthreads();
        if (tid < 128) {
            partial[(size_t)blockIdx.x * 256 + tid] =
                st_s[0][tid] + st_s[1][tid] + st_s[2][tid] + st_s[3][tid];
            partial[(size_t)blockIdx.x * 256 + 128 + tid] =
                st_q[0][tid] + st_q[1][tid] + st_q[2][tid] + st_q[3][tid];
        }
    }
}

// ---------------- BN reduce: 128 blocks, one column each ----------------
__global__ __launch_bounds__(256) void bn_reduce_kernel(
        const float* __restrict__ partial,
        const float* __restrict__ g, const float* __restrict__ bt,
        float* __restrict__ scale, float* __restrict__ shift) {
    __shared__ float ss[256], sq[256];
    int j = blockIdx.x;       // 0..127
    int tid = threadIdx.x;    // 0..255
    float s = 0.f, q = 0.f;
    for (int b = tid; b < GEMM_NBLK; b += 256) {
        s += partial[(size_t)b * 256 + j];
        q += partial[(size_t)b * 256 + 128 + j];
    }
    ss[tid] = s; sq[tid] = q;
    __syncthreads();
    for (int off = 128; off > 0; off >>= 1) {
        if (tid < off) { ss[tid] += ss[tid + off]; sq[tid] += sq[tid + off]; }
        __syncthreads();
    }
    if (tid == 0) {
        float m = ss[0] / (float)N_NODES;
        float v = sq[0] / (float)N_NODES - m * m;
        float sc = g[j] * rsqrtf(v + BN_EPS);
        scale[j] = sc;
        shift[j] = bt[j] - m * sc;
    }
}

// ---------------- launch ----------------

extern "C" void kernel_launch(void* const* d_in, const int* in_sizes, int n_in,
                              void* d_out, int out_size, void* d_ws, size_t ws_size,
                              hipStream_t stream) {
    const float* x   = (const float*)d_in[0];
    const int*   ei  = (const int*)d_in[1];
    const float* W1  = (const float*)d_in[2];
    const float* b1  = (const float*)d_in[3];
    const float* W2  = (const float*)d_in[4];
    const float* b2  = (const float*)d_in[5];
    const float* W3  = (const float*)d_in[6];
    const float* b3  = (const float*)d_in[7];
    const float* g1  = (const float*)d_in[8];
    const float* bt1 = (const float*)d_in[9];
    const float* g2  = (const float*)d_in[10];
    const float* bt2 = (const float*)d_in[11];
    float* out = (float*)d_out;

    const int* row = ei;
    const int* col = ei + N_EDGES;

    char* ws = (char*)d_ws;
    size_t off = 0;
    auto alloc = [&](size_t bytes) -> void* {
        void* p = ws + off;
        off += (bytes + 255) & ~(size_t)255;
        return p;
    };
    int*   rowptr   = (int*)alloc((N_NODES + 1) * 4);
    int*   localscan= (int*)alloc(N_NODES * 4);
    int*   blocksum = (int*)alloc(NB_SCAN * 4);
    float* dinv     = (float*)alloc(N_NODES * 4);
    unsigned int* colwt = (unsigned int*)alloc((size_t)N_EDGES * 4);
    _Float16* Bp    = (_Float16*)alloc(3 * 32768 * 2);
    float* partial  = (float*)alloc((size_t)GEMM_NBLK * 256 * 4);
    float* scale1   = (float*)alloc(F * 4);
    float* shift1   = (float*)alloc(F * 4);
    float* scale2   = (float*)alloc(F * 4);
    float* shift2   = (float*)alloc(F * 4);
    __half* xh      = (__half*)alloc((size_t)N_NODES * F * 2);
    __half* hpA     = (__half*)alloc((size_t)(N_NODES + 64) * F * 2);  // pad for last gemm block
    __half* hB      = (__half*)alloc((size_t)N_NODES * F * 2);
    // subhist (32 x 50000 ints = 6.4 MB) aliases hB: dead before gemm0 writes hB.
    int* subhist    = (int*)hB;
    (void)ws_size; (void)n_in; (void)in_sizes; (void)out_size;

    prep_kernel<<<NB_X2H + NB_PB + NB_HIST, 256, 0, stream>>>(
        x, xh, W1, W2, W3, Bp, row, subhist);
    scan_block<<<NB_SCAN, 256, 0, stream>>>(subhist, localscan, blocksum, dinv);
    scan_add_tops<<<NB_SCAN, 256, 0, stream>>>(localscan, blocksum, rowptr);
    fill_kernel<<<NB_HIST, 256, 0, stream>>>(row, col, rowptr, subhist, dinv, colwt);

    const int hp_grid = N_NODES / 4;  // 4 waves/block, 1 row per wave

    // layer 0
    hp_kernel<0><<<hp_grid, 256, 0, stream>>>(xh, nullptr, nullptr, dinv, rowptr,
                                              colwt, hpA);
    gemm_kernel<0><<<GEMM_NBLK, 256, 0, stream>>>(hpA, Bp, b1, hB, partial, N_NODES);
    bn_reduce_kernel<<<128, 256, 0, stream>>>(partial, g1, bt1, scale1, shift1);

    // layer 1
    hp_kernel<1><<<hp_grid, 256, 0, stream>>>(hB, scale1, shift1, dinv, rowptr,
                                              colwt, hpA);
    gemm_kernel<0><<<GEMM_NBLK, 256, 0, stream>>>(hpA, Bp + 32768, b2, hB, partial,
                                                  N_NODES);
    bn_reduce_kernel<<<128, 256, 0, stream>>>(partial, g2, bt2, scale2, shift2);

    // layer 2 (output, f32)
    hp_kernel<1><<<hp_grid, 256, 0, stream>>>(hB, scale2, shift2, dinv, rowptr,
                                              colwt, hpA);
    gemm_kernel<1><<<GEMM_NBLK, 256, 0, stream>>>(hpA, Bp + 65536, b3, out, nullptr,
                                                  N_NODES);
}

// Round 10
// 190.780 us; speedup vs baseline: 4.4298x; 1.1363x over previous
//
#include <hip/hip_runtime.h>
#include <hip/hip_fp16.h>

#define N_NODES 50000
#define N_EDGES 800000
#define F 128
#define ALPHA 0.5f
#define BN_EPS 1e-5f
#define NB_SCAN ((N_NODES + 255) / 256)   // 196
#define GEMM_NBLK ((N_NODES + 63) / 64)   // 782
#define NGRP 8
#define GRP_ROWS (N_NODES / NGRP)         // 6250
#define NCHUNK 64
#define CHUNK_I4 (N_EDGES / NCHUNK / 4)   // 3125 int4 per chunk (12500 edges)
#define PREP_THREADS 1024
#define NB_X2H ((N_NODES * F / 8 + PREP_THREADS - 1) / PREP_THREADS)  // 782
#define NB_PB 6
#define NB_HIST (NGRP * NCHUNK)           // 512

typedef _Float16 half8_t __attribute__((ext_vector_type(8)));
typedef float floatx4 __attribute__((ext_vector_type(4)));

union H8 { uint4 u; __half2 h2[4]; };

// ---------------- fused prep: x->fp16 | pack B | LDS-hist counting ----------------
// blocks [0,782): x2half ; [782,788): pack_b ; [788,1300): subhist
__global__ __launch_bounds__(PREP_THREADS) void prep_kernel(
        const float* __restrict__ x, __half* __restrict__ xh,
        const float* __restrict__ W1, const float* __restrict__ W2,
        const float* __restrict__ W3, _Float16* __restrict__ Bp,
        const int* __restrict__ row, int* __restrict__ subhist) {
    int bid = blockIdx.x;
    if (bid < NB_X2H) {
        int idx = bid * PREP_THREADS + threadIdx.x;   // one per 8 elems
        if (idx < N_NODES * F / 8) {
            float4 f0 = ((const float4*)x)[idx * 2];
            float4 f1 = ((const float4*)x)[idx * 2 + 1];
            H8 o;
            o.h2[0] = __float22half2_rn(make_float2(f0.x, f0.y));
            o.h2[1] = __float22half2_rn(make_float2(f0.z, f0.w));
            o.h2[2] = __float22half2_rn(make_float2(f1.x, f1.y));
            o.h2[3] = __float22half2_rn(make_float2(f1.z, f1.w));
            ((uint4*)xh)[idx] = o.u;
        }
    } else if (bid < NB_X2H + NB_PB) {
        // B[k][n] = W[n][k]; lane holds B[k0+(lane>>4)*8+j][n0*16+(lane&15)]
        int idx = (bid - NB_X2H) * PREP_THREADS + threadIdx.x;   // 3*2048 = 6144
        int layer = idx >> 11;
        int r = idx & 2047;
        int t = r >> 6, lane = r & 63;
        int s = t >> 3, n0 = t & 7;
        int n = n0 * 16 + (lane & 15);
        int k = s * 32 + (lane >> 4) * 8;
        const float* W = (layer == 0) ? W1 : (layer == 1) ? W2 : W3;
        float4 f0 = *(const float4*)(W + n * 128 + k);
        float4 f1 = *(const float4*)(W + n * 128 + k + 4);
        _Float16* dst = Bp + (size_t)layer * 32768 + (size_t)r * 8;
        dst[0] = (_Float16)f0.x; dst[1] = (_Float16)f0.y;
        dst[2] = (_Float16)f0.z; dst[3] = (_Float16)f0.w;
        dst[4] = (_Float16)f1.x; dst[5] = (_Float16)f1.y;
        dst[6] = (_Float16)f1.z; dst[7] = (_Float16)f1.w;
    } else {
        // subhist[c][i] = #edges in chunk c with row i (row-group g only)
        int t = bid - (NB_X2H + NB_PB);
        int g = t & 7, c = t >> 3;    // t%8 keeps group g on one XCD
        int rlo = g * GRP_ROWS;
        __shared__ int hist[GRP_ROWS];
        for (int j = threadIdx.x; j < GRP_ROWS; j += PREP_THREADS) hist[j] = 0;
        __syncthreads();
        const int4* r4 = (const int4*)row;
        for (int v = c * CHUNK_I4 + threadIdx.x; v < (c + 1) * CHUNK_I4;
             v += PREP_THREADS) {
            int4 rr = r4[v];
            if ((unsigned)(rr.x - rlo) < GRP_ROWS) atomicAdd(&hist[rr.x - rlo], 1);
            if ((unsigned)(rr.y - rlo) < GRP_ROWS) atomicAdd(&hist[rr.y - rlo], 1);
            if ((unsigned)(rr.z - rlo) < GRP_ROWS) atomicAdd(&hist[rr.z - rlo], 1);
            if ((unsigned)(rr.w - rlo) < GRP_ROWS) atomicAdd(&hist[rr.w - rlo], 1);
        }
        __syncthreads();
        for (int j = threadIdx.x; j < GRP_ROWS; j += PREP_THREADS)
            subhist[(size_t)c * N_NODES + rlo + j] = hist[j];
    }
}

// ---------------- scan: chunk-offsets (in place) + deg/dinv + block scan ----------------

__global__ void scan_block(int* __restrict__ subhist, int* __restrict__ localscan,
                           int* __restrict__ blocksum, float* __restrict__ dinv) {
    __shared__ int s[256];
    int i = blockIdx.x * 256 + threadIdx.x;
    int deg = 0;
    if (i < N_NODES) {
        for (int c = 0; c < NCHUNK; ++c) {
            int t = subhist[(size_t)c * N_NODES + i];
            subhist[(size_t)c * N_NODES + i] = deg;   // exclusive prefix over chunks
            deg += t;
        }
        dinv[i] = deg > 0 ? rsqrtf((float)deg) : 0.f;
    }
    s[threadIdx.x] = deg;
    __syncthreads();
    for (int off = 1; off < 256; off <<= 1) {
        int t = (threadIdx.x >= off) ? s[threadIdx.x - off] : 0;
        __syncthreads();
        s[threadIdx.x] += t;
        __syncthreads();
    }
    if (i < N_NODES) localscan[i] = s[threadIdx.x];
    if (threadIdx.x == 255) blocksum[blockIdx.x] = s[255];
}

// every block re-scans the 196 block sums in LDS (exclusive prefix of own bid)
__global__ void scan_add_tops(const int* __restrict__ localscan,
                              const int* __restrict__ blocksum,
                              int* __restrict__ rowptr) {
    __shared__ int s[256];
    int v = (threadIdx.x < NB_SCAN) ? blocksum[threadIdx.x] : 0;
    s[threadIdx.x] = v;
    __syncthreads();
    for (int off = 1; off < 256; off <<= 1) {
        int t = (threadIdx.x >= off) ? s[threadIdx.x - off] : 0;
        __syncthreads();
        s[threadIdx.x] += t;
        __syncthreads();
    }
    int base = (blockIdx.x > 0) ? s[blockIdx.x - 1] : 0;
    int i = blockIdx.x * 256 + threadIdx.x;
    if (i < N_NODES) rowptr[i + 1] = localscan[i] + base;
    if (i == 0) rowptr[0] = 0;
}

// ---------------- fill: LDS-cursor counting-sort scatter (no global atomics) ----------------
// packed 4B edge record {u16 col, f16 dinv[col]}

__global__ __launch_bounds__(PREP_THREADS) void fill_kernel(
        const int* __restrict__ row, const int* __restrict__ col,
        const int* __restrict__ rowptr, const int* __restrict__ chunkoff,
        const float* __restrict__ dinv, unsigned int* __restrict__ colwt) {
    int t = blockIdx.x;           // 512 blocks: g = t&7, c = t>>3
    int g = t & 7, c = t >> 3;
    int rlo = g * GRP_ROWS;
    __shared__ int cur[GRP_ROWS];
    for (int j = threadIdx.x; j < GRP_ROWS; j += PREP_THREADS)
        cur[j] = rowptr[rlo + j] + chunkoff[(size_t)c * N_NODES + rlo + j];
    __syncthreads();
    const int4* r4 = (const int4*)row;
    const int4* c4 = (const int4*)col;
    for (int v = c * CHUNK_I4 + threadIdx.x; v < (c + 1) * CHUNK_I4;
         v += PREP_THREADS) {
        int4 rr = r4[v];
        int4 cc = c4[v];
        int rs[4] = {rr.x, rr.y, rr.z, rr.w};
        int cs[4] = {cc.x, cc.y, cc.z, cc.w};
        #pragma unroll
        for (int k = 0; k < 4; ++k) {
            if ((unsigned)(rs[k] - rlo) < GRP_ROWS) {
                int pos = atomicAdd(&cur[rs[k] - rlo], 1);
                unsigned int hb = __half_as_ushort(__float2half(dinv[cs[k]]));
                colwt[pos] = (unsigned int)cs[k] | (hb << 16);
            }
        }
    }
}

// ---------------- fused high-pass (fp16 rows, quarter-wave per edge) ----------------
template <int USEBN>
__global__ __launch_bounds__(256) void hp_kernel(
        const __half* __restrict__ h,
        const float* __restrict__ scale, const float* __restrict__ shift,
        const float* __restrict__ dinv, const int* __restrict__ rowptr,
        const unsigned int* __restrict__ colwt, __half* __restrict__ out) {
    int lane = threadIdx.x & 63;
    int q = lane >> 4;
    int l = lane & 15;
    int i = blockIdx.x * 4 + (threadIdx.x >> 6);   // 4 waves/block, 1 row each

    float sc[8], sh[8];
    if (USEBN) {
        float4 a0 = ((const float4*)scale)[l * 2];
        float4 a1 = ((const float4*)scale)[l * 2 + 1];
        float4 b0 = ((const float4*)shift)[l * 2];
        float4 b1 = ((const float4*)shift)[l * 2 + 1];
        sc[0] = a0.x; sc[1] = a0.y; sc[2] = a0.z; sc[3] = a0.w;
        sc[4] = a1.x; sc[5] = a1.y; sc[6] = a1.z; sc[7] = a1.w;
        sh[0] = b0.x; sh[1] = b0.y; sh[2] = b0.z; sh[3] = b0.w;
        sh[4] = b1.x; sh[5] = b1.y; sh[6] = b1.z; sh[7] = b1.w;
    }

    int e0 = rowptr[i], e1 = rowptr[i + 1];
    const char* hb = (const char*)h;
    int loff = l * 16;
    float acc[8] = {0.f, 0.f, 0.f, 0.f, 0.f, 0.f, 0.f, 0.f};

    int e = e0 + q;
    for (; e + 4 < e1; e += 8) {   // 2 edges per quarter per iter
        unsigned int cw0 = colwt[e];
        unsigned int cw1 = colwt[e + 4];
        H8 r0, r1;
        r0.u = *(const uint4*)(hb + (size_t)(cw0 & 0xffffu) * 256 + loff);
        r1.u = *(const uint4*)(hb + (size_t)(cw1 & 0xffffu) * 256 + loff);
        float w0 = __half2float(__ushort_as_half((unsigned short)(cw0 >> 16)));
        float w1 = __half2float(__ushort_as_half((unsigned short)(cw1 >> 16)));
        #pragma unroll
        for (int p = 0; p < 4; ++p) {
            float2 f0 = __half22float2(r0.h2[p]);
            float2 f1 = __half22float2(r1.h2[p]);
            if (USEBN) {
                f0.x = fmaxf(fmaf(f0.x, sc[2 * p], sh[2 * p]), 0.f);
                f0.y = fmaxf(fmaf(f0.y, sc[2 * p + 1], sh[2 * p + 1]), 0.f);
                f1.x = fmaxf(fmaf(f1.x, sc[2 * p], sh[2 * p]), 0.f);
                f1.y = fmaxf(fmaf(f1.y, sc[2 * p + 1], sh[2 * p + 1]), 0.f);
            }
            acc[2 * p]     = fmaf(w0, f0.x, acc[2 * p]);
            acc[2 * p + 1] = fmaf(w0, f0.y, acc[2 * p + 1]);
            acc[2 * p]     = fmaf(w1, f1.x, acc[2 * p]);
            acc[2 * p + 1] = fmaf(w1, f1.y, acc[2 * p + 1]);
        }
    }
    for (; e < e1; e += 4) {
        unsigned int cw = colwt[e];
        H8 r0;
        r0.u = *(const uint4*)(hb + (size_t)(cw & 0xffffu) * 256 + loff);
        float w0 = __half2float(__ushort_as_half((unsigned short)(cw >> 16)));
        #pragma unroll
        for (int p = 0; p < 4; ++p) {
            float2 f0 = __half22float2(r0.h2[p]);
            if (USEBN) {
                f0.x = fmaxf(fmaf(f0.x, sc[2 * p], sh[2 * p]), 0.f);
                f0.y = fmaxf(fmaf(f0.y, sc[2 * p + 1], sh[2 * p + 1]), 0.f);
            }
            acc[2 * p]     = fmaf(w0, f0.x, acc[2 * p]);
            acc[2 * p + 1] = fmaf(w0, f0.y, acc[2 * p + 1]);
        }
    }

    #pragma unroll
    for (int c = 0; c < 8; ++c) {
        acc[c] += __shfl_xor(acc[c], 16);
        acc[c] += __shfl_xor(acc[c], 32);
    }

    float a = ALPHA * dinv[i];
    if (q == 0) {
        H8 s8, o;
        s8.u = *(const uint4*)(hb + (size_t)i * 256 + loff);
        #pragma unroll
        for (int p = 0; p < 4; ++p) {
            float2 f = __half22float2(s8.h2[p]);
            if (USEBN) {
                f.x = fmaxf(fmaf(f.x, sc[2 * p], sh[2 * p]), 0.f);
                f.y = fmaxf(fmaf(f.y, sc[2 * p + 1], sh[2 * p + 1]), 0.f);
            }
            o.h2[p] = __float22half2_rn(
                make_float2(f.x - a * acc[2 * p], f.y - a * acc[2 * p + 1]));
        }
        *(uint4*)((char*)out + (size_t)i * 256 + loff) = o.u;
    }
}

// ---------------- MFMA GEMM: out[M x 128] = A_half @ B + bias ----------------
// MODE 0: half out + fused BN col partials; MODE 1: f32 out, no stats.
template <int MODE>
__global__ __launch_bounds__(256) void gemm_kernel(
        const __half* __restrict__ A, const _Float16* __restrict__ Bp,
        const float* __restrict__ bias, void* __restrict__ outv,
        float* __restrict__ partial, int M) {
    __shared__ float st_s[4][128];
    __shared__ float st_q[4][128];
    int tid = threadIdx.x;
    int w = tid >> 6, lane = tid & 63;
    int l = lane & 15, g = lane >> 4;
    int row0 = blockIdx.x * 64 + w * 16;
    bool active = row0 < M;   // M % 16 == 0, so waves are all-or-nothing

    const char* Ab = (const char*)A;
    half8_t a[4];
    if (active) {
        #pragma unroll
        for (int s = 0; s < 4; ++s)
            a[s] = *(const half8_t*)(Ab + (size_t)(row0 + l) * 256 + s * 64 + g * 16);
    } else {
        half8_t z = 0;
        a[0] = z; a[1] = z; a[2] = z; a[3] = z;
    }

    #pragma unroll
    for (int n0 = 0; n0 < 8; ++n0) {
        floatx4 acc = {0.f, 0.f, 0.f, 0.f};
        #pragma unroll
        for (int s = 0; s < 4; ++s) {
            half8_t b = *(const half8_t*)(Bp + ((size_t)(s * 8 + n0) * 64 + lane) * 8);
            acc = __builtin_amdgcn_mfma_f32_16x16x32_f16(a[s], b, acc, 0, 0, 0);
        }
        int col = n0 * 16 + l;
        float bv = bias[col];
        float v0 = acc[0] + bv, v1 = acc[1] + bv, v2 = acc[2] + bv, v3 = acc[3] + bv;
        if (active) {
            int r = row0 + g * 4;
            if (MODE == 0) {
                __half* oh = (__half*)outv;
                oh[(size_t)r * 128 + col]       = __float2half_rn(v0);
                oh[(size_t)(r + 1) * 128 + col] = __float2half_rn(v1);
                oh[(size_t)(r + 2) * 128 + col] = __float2half_rn(v2);
                oh[(size_t)(r + 3) * 128 + col] = __float2half_rn(v3);
            } else {
                float* of = (float*)outv;
                of[(size_t)r * 128 + col]       = v0;
                of[(size_t)(r + 1) * 128 + col] = v1;
                of[(size_t)(r + 2) * 128 + col] = v2;
                of[(size_t)(r + 3) * 128 + col] = v3;
            }
        } else {
            v0 = v1 = v2 = v3 = 0.f;
        }
        if (MODE == 0) {
            float s_ = v0 + v1 + v2 + v3;
            float q_ = v0 * v0 + v1 * v1 + v2 * v2 + v3 * v3;
            s_ += __shfl_xor(s_, 16); s_ += __shfl_xor(s_, 32);
            q_ += __shfl_xor(q_, 16); q_ += __shfl_xor(q_, 32);
            if (lane < 16) { st_s[w][col] = s_; st_q[w][col] = q_; }
        }
    }
    if (MODE == 0) {
        __syncthreads();
        if (tid < 128) {
            partial[(size_t)blockIdx.x * 256 + tid] =
                st_s[0][tid] + st_s[1][tid] + st_s[2][tid] + st_s[3][tid];
            partial[(size_t)blockIdx.x * 256 + 128 + tid] =
                st_q[0][tid] + st_q[1][tid] + st_q[2][tid] + st_q[3][tid];
        }
    }
}

// ---------------- BN reduce: 128 blocks, one column each ----------------
__global__ __launch_bounds__(256) void bn_reduce_kernel(
        const float* __restrict__ partial,
        const float* __restrict__ g, const float* __restrict__ bt,
        float* __restrict__ scale, float* __restrict__ shift) {
    __shared__ float ss[256], sq[256];
    int j = blockIdx.x;       // 0..127
    int tid = threadIdx.x;    // 0..255
    float s = 0.f, q = 0.f;
    for (int b = tid; b < GEMM_NBLK; b += 256) {
        s += partial[(size_t)b * 256 + j];
        q += partial[(size_t)b * 256 + 128 + j];
    }
    ss[tid] = s; sq[tid] = q;
    __syncthreads();
    for (int off = 128; off > 0; off >>= 1) {
        if (tid < off) { ss[tid] += ss[tid + off]; sq[tid] += sq[tid + off]; }
        __syncthreads();
    }
    if (tid == 0) {
        float m = ss[0] / (float)N_NODES;
        float v = sq[0] / (float)N_NODES - m * m;
        float sc = g[j] * rsqrtf(v + BN_EPS);
        scale[j] = sc;
        shift[j] = bt[j] - m * sc;
    }
}

// ---------------- launch ----------------

extern "C" void kernel_launch(void* const* d_in, const int* in_sizes, int n_in,
                              void* d_out, int out_size, void* d_ws, size_t ws_size,
                              hipStream_t stream) {
    const float* x   = (const float*)d_in[0];
    const int*   ei  = (const int*)d_in[1];
    const float* W1  = (const float*)d_in[2];
    const float* b1  = (const float*)d_in[3];
    const float* W2  = (const float*)d_in[4];
    const float* b2  = (const float*)d_in[5];
    const float* W3  = (const float*)d_in[6];
    const float* b3  = (const float*)d_in[7];
    const float* g1  = (const float*)d_in[8];
    const float* bt1 = (const float*)d_in[9];
    const float* g2  = (const float*)d_in[10];
    const float* bt2 = (const float*)d_in[11];
    float* out = (float*)d_out;

    const int* row = ei;
    const int* col = ei + N_EDGES;

    char* ws = (char*)d_ws;
    size_t off = 0;
    auto alloc = [&](size_t bytes) -> void* {
        void* p = ws + off;
        off += (bytes + 255) & ~(size_t)255;
        return p;
    };
    int*   rowptr   = (int*)alloc((N_NODES + 1) * 4);
    int*   localscan= (int*)alloc(N_NODES * 4);
    int*   blocksum = (int*)alloc(NB_SCAN * 4);
    float* dinv     = (float*)alloc(N_NODES * 4);
    unsigned int* colwt = (unsigned int*)alloc((size_t)N_EDGES * 4);
    _Float16* Bp    = (_Float16*)alloc(3 * 32768 * 2);
    float* partial  = (float*)alloc((size_t)GEMM_NBLK * 256 * 4);
    float* scale1   = (float*)alloc(F * 4);
    float* shift1   = (float*)alloc(F * 4);
    float* scale2   = (float*)alloc(F * 4);
    float* shift2   = (float*)alloc(F * 4);
    __half* xh      = (__half*)alloc((size_t)N_NODES * F * 2);
    __half* hpA     = (__half*)alloc((size_t)(N_NODES + 64) * F * 2);  // pad for last gemm block
    __half* hB      = (__half*)alloc((size_t)N_NODES * F * 2);
    // subhist (64 x 50000 ints = 12.8 MB) aliases hB: dead before gemm0 writes hB.
    int* subhist    = (int*)hB;
    (void)ws_size; (void)n_in; (void)in_sizes; (void)out_size;

    prep_kernel<<<NB_X2H + NB_PB + NB_HIST, PREP_THREADS, 0, stream>>>(
        x, xh, W1, W2, W3, Bp, row, subhist);
    scan_block<<<NB_SCAN, 256, 0, stream>>>(subhist, localscan, blocksum, dinv);
    scan_add_tops<<<NB_SCAN, 256, 0, stream>>>(localscan, blocksum, rowptr);
    fill_kernel<<<NB_HIST, PREP_THREADS, 0, stream>>>(row, col, rowptr, subhist,
                                                      dinv, colwt);

    const int hp_grid = N_NODES / 4;  // 4 waves/block, 1 row per wave

    // layer 0
    hp_kernel<0><<<hp_grid, 256, 0, stream>>>(xh, nullptr, nullptr, dinv, rowptr,
                                              colwt, hpA);
    gemm_kernel<0><<<GEMM_NBLK, 256, 0, stream>>>(hpA, Bp, b1, hB, partial, N_NODES);
    bn_reduce_kernel<<<128, 256, 0, stream>>>(partial, g1, bt1, scale1, shift1);

    // layer 1
    hp_kernel<1><<<hp_grid, 256, 0, stream>>>(hB, scale1, shift1, dinv, rowptr,
                                              colwt, hpA);
    gemm_kernel<0><<<GEMM_NBLK, 256, 0, stream>>>(hpA, Bp + 32768, b2, hB, partial,
                                                  N_NODES);
    bn_reduce_kernel<<<128, 256, 0, stream>>>(partial, g2, bt2, scale2, shift2);

    // layer 2 (output, f32)
    hp_kernel<1><<<hp_grid, 256, 0, stream>>>(hB, scale2, shift2, dinv, rowptr,
                                              colwt, hpA);
    gemm_kernel<1><<<GEMM_NBLK, 256, 0, stream>>>(hpA, Bp + 65536, b3, out, nullptr,
                                                  N_NODES);
}